// Round 1
// baseline (8780.680 us; speedup 1.0000x reference)
//
#include <hip/hip_runtime.h>
#include <hip/hip_bf16.h>
#include <math.h>

// Problem dims (fixed by setup_inputs)
#define T_DIM 128
#define B_DIM 128
#define S_DIM 8
#define DIN   64
#define R_DIM 256
#define Z_DIM 128
#define H_DIM 512
#define C_DIM 32
#define CH_DIM 64

#define DT_F      0.05f
#define SQRT_DT_F 0.22360679774997896f
#define LOG_2PI_F 1.8378770664093453f

__device__ __forceinline__ float tanh_fast(float x) {
    // tanh via hw exp; no NaN for large |x| (e underflows to 0 -> r=1)
    float ax = fabsf(x);
    float e  = __expf(-2.0f * ax);
    float r  = (1.0f - e) / (1.0f + e);
    return copysignf(r, x);
}

// ---------------------------------------------------------------------------
// K0: z0 = tanh(mlp(cov)) broadcast to (B,S,Z); zero loss accumulators.
// grid: B blocks x 128 threads
// ---------------------------------------------------------------------------
__global__ __launch_bounds__(128) void k0_init(
    const float* __restrict__ cov,
    const float* __restrict__ Wc1, const float* __restrict__ bc1,
    const float* __restrict__ Wc2, const float* __restrict__ bc2,
    float* __restrict__ z_state, float* __restrict__ loss_acc)
{
    int b = blockIdx.x;
    int tid = threadIdx.x;
    __shared__ float covs[C_DIM];
    __shared__ float hid[CH_DIM];
    if (tid < C_DIM) covs[tid] = cov[b * C_DIM + tid];
    __syncthreads();
    if (tid < CH_DIM) {
        float a = bc1[tid];
        #pragma unroll
        for (int c = 0; c < C_DIM; ++c) a = fmaf(covs[c], Wc1[c * CH_DIM + tid], a);
        hid[tid] = fmaxf(a, 0.0f);
    }
    __syncthreads();
    // tid in [0,128): z column
    float a = bc2[tid];
    #pragma unroll 8
    for (int h = 0; h < CH_DIM; ++h) a = fmaf(hid[h], Wc2[h * Z_DIM + tid], a);
    float z0 = tanh_fast(a);
    #pragma unroll
    for (int s = 0; s < S_DIM; ++s)
        z_state[((size_t)b * S_DIM + s) * Z_DIM + tid] = z0;
    if (b == 0 && tid < 2) loss_acc[tid] = 0.0f;
}

// ---------------------------------------------------------------------------
// K1: precompute (for t in [t0, t0+chunk)):
//   Hprior[t,b,:] = h  @ Wd1[:R]        (H_DIM)
//   Hpost [t,b,:] = (h+hpos) @ Wd1[:R]
//   Hp    [t,b,:] = h  @ Wp1[:R]
//   Diff  [t,b,:] = exp(relu(h@Wf1+bf1)@Wf2+bf2)   (Z_DIM)
//   MtM   [t,b]   = mean(M[t,b,:])
// grid: chunk*8 blocks (16 b-rows per block, one t per block) x 256 threads
// ---------------------------------------------------------------------------
__global__ __launch_bounds__(256) void k1_pre(
    const float* __restrict__ path_h, const float* __restrict__ path_hpos,
    const float* __restrict__ M,
    const float* __restrict__ Wd1,
    const float* __restrict__ Wf1, const float* __restrict__ bf1,
    const float* __restrict__ Wf2, const float* __restrict__ bf2,
    const float* __restrict__ Wp1,
    float* __restrict__ Hprior, float* __restrict__ Hpost, float* __restrict__ Hp,
    float* __restrict__ Diff, float* __restrict__ MtM,
    int t0)
{
    int tl = blockIdx.x >> 3;
    int t  = t0 + tl;
    int b0 = (blockIdx.x & 7) << 4;     // 16 consecutive b
    int tid = threadIdx.x;

    __shared__ float A [16][R_DIM];     // path_h rows
    __shared__ float As[16][R_DIM];     // h + hpos
    __shared__ float fh[16][H_DIM];     // relu hidden for diffusion
    __shared__ float red[256];

    // stage A tiles (contiguous 16KB each)
    {
        const float4* src  = (const float4*)(path_h    + ((size_t)t * B_DIM + b0) * R_DIM);
        const float4* srcp = (const float4*)(path_hpos + ((size_t)t * B_DIM + b0) * R_DIM);
        float4* Ad  = (float4*)&A[0][0];
        float4* Asd = (float4*)&As[0][0];
        for (int i = tid; i < 16 * R_DIM / 4; i += 256) {
            float4 v = src[i], vp = srcp[i];
            Ad[i] = v;
            Asd[i] = make_float4(v.x + vp.x, v.y + vp.y, v.z + vp.z, v.w + vp.w);
        }
    }
    __syncthreads();

    int r0 = (tid >> 6) << 2;   // 4 rows: r0..r0+3
    int c0 = tid & 63;          // 8 cols: c0 + 64*i

    // ---- P1: Hprior & Hpost
    {
        float accP[4][8], accQ[4][8];
        #pragma unroll
        for (int r = 0; r < 4; ++r)
            #pragma unroll
            for (int i = 0; i < 8; ++i) { accP[r][i] = 0.f; accQ[r][i] = 0.f; }
        for (int k = 0; k < R_DIM; k += 4) {
            float av[4][4], sv[4][4];
            #pragma unroll
            for (int r = 0; r < 4; ++r) {
                *(float4*)av[r] = *(const float4*)&A [r0 + r][k];
                *(float4*)sv[r] = *(const float4*)&As[r0 + r][k];
            }
            #pragma unroll
            for (int kk = 0; kk < 4; ++kk) {
                const float* wrow = Wd1 + (size_t)(k + kk) * H_DIM + c0;
                #pragma unroll
                for (int i = 0; i < 8; ++i) {
                    float w = wrow[i * 64];
                    #pragma unroll
                    for (int r = 0; r < 4; ++r) {
                        accP[r][i] = fmaf(av[r][kk], w, accP[r][i]);
                        accQ[r][i] = fmaf(sv[r][kk], w, accQ[r][i]);
                    }
                }
            }
        }
        #pragma unroll
        for (int r = 0; r < 4; ++r)
            #pragma unroll
            for (int i = 0; i < 8; ++i) {
                size_t o = ((size_t)tl * B_DIM + b0 + r0 + r) * H_DIM + c0 + i * 64;
                Hprior[o] = accP[r][i];
                Hpost [o] = accQ[r][i];
            }
    }

    // ---- P2a: fh = relu(A @ Wf1 + bf1)
    {
        float accF[4][8];
        #pragma unroll
        for (int r = 0; r < 4; ++r)
            #pragma unroll
            for (int i = 0; i < 8; ++i) accF[r][i] = 0.f;
        for (int k = 0; k < R_DIM; k += 4) {
            float av[4][4];
            #pragma unroll
            for (int r = 0; r < 4; ++r)
                *(float4*)av[r] = *(const float4*)&A[r0 + r][k];
            #pragma unroll
            for (int kk = 0; kk < 4; ++kk) {
                const float* wrow = Wf1 + (size_t)(k + kk) * H_DIM + c0;
                #pragma unroll
                for (int i = 0; i < 8; ++i) {
                    float w = wrow[i * 64];
                    #pragma unroll
                    for (int r = 0; r < 4; ++r) accF[r][i] = fmaf(av[r][kk], w, accF[r][i]);
                }
            }
        }
        #pragma unroll
        for (int r = 0; r < 4; ++r)
            #pragma unroll
            for (int i = 0; i < 8; ++i)
                fh[r0 + r][c0 + i * 64] = fmaxf(accF[r][i] + bf1[c0 + i * 64], 0.f);
    }
    __syncthreads();

    // ---- P2b: Diff = exp(fh @ Wf2 + bf2)
    {
        int j  = tid & 127;
        int rg = (tid >> 7) << 3;   // rows rg..rg+7
        float acc[8];
        #pragma unroll
        for (int r = 0; r < 8; ++r) acc[r] = 0.f;
        for (int h = 0; h < H_DIM; h += 4) {
            float fv[8][4];
            #pragma unroll
            for (int r = 0; r < 8; ++r)
                *(float4*)fv[r] = *(const float4*)&fh[rg + r][h];
            #pragma unroll
            for (int hh = 0; hh < 4; ++hh) {
                float w = Wf2[(size_t)(h + hh) * Z_DIM + j];
                #pragma unroll
                for (int r = 0; r < 8; ++r) acc[r] = fmaf(fv[r][hh], w, acc[r]);
            }
        }
        float bj = bf2[j];
        #pragma unroll
        for (int r = 0; r < 8; ++r)
            Diff[((size_t)tl * B_DIM + b0 + rg + r) * Z_DIM + j] = __expf(acc[r] + bj);
    }

    // ---- P3: Hp = A @ Wp1[:R]
    {
        float accH[4][8];
        #pragma unroll
        for (int r = 0; r < 4; ++r)
            #pragma unroll
            for (int i = 0; i < 8; ++i) accH[r][i] = 0.f;
        for (int k = 0; k < R_DIM; k += 4) {
            float av[4][4];
            #pragma unroll
            for (int r = 0; r < 4; ++r)
                *(float4*)av[r] = *(const float4*)&A[r0 + r][k];
            #pragma unroll
            for (int kk = 0; kk < 4; ++kk) {
                const float* wrow = Wp1 + (size_t)(k + kk) * H_DIM + c0;
                #pragma unroll
                for (int i = 0; i < 8; ++i) {
                    float w = wrow[i * 64];
                    #pragma unroll
                    for (int r = 0; r < 4; ++r) accH[r][i] = fmaf(av[r][kk], w, accH[r][i]);
                }
            }
        }
        #pragma unroll
        for (int r = 0; r < 4; ++r)
            #pragma unroll
            for (int i = 0; i < 8; ++i)
                Hp[((size_t)tl * B_DIM + b0 + r0 + r) * H_DIM + c0 + i * 64] = accH[r][i];
    }

    // ---- MtM = mean(M[t,b,:])
    {
        int row = tid >> 4, d0 = (tid & 15) << 2;
        float4 mv = *(const float4*)(M + ((size_t)t * B_DIM + b0 + row) * DIN + d0);
        red[tid] = mv.x + mv.y + mv.z + mv.w;
        __syncthreads();
        if ((tid & 15) == 0) {
            float s = 0.f;
            #pragma unroll
            for (int i = 0; i < 16; ++i) s += red[(row << 4) + i];
            MtM[(size_t)tl * B_DIM + b0 + row] = s * (1.0f / 64.0f);
        }
    }
}

// ---------------------------------------------------------------------------
// K2: sequential scan over t in [t0, t0+nt). 256 blocks x 256 threads.
// Each block owns (b = blk>>1, s in [4*(blk&1), +4)) -> 4 rows, no grid sync.
// ---------------------------------------------------------------------------
__global__ __launch_bounds__(256) void k2_scan(
    const float* __restrict__ X, const float* __restrict__ noise,
    const float* __restrict__ Wd1, const float* __restrict__ bd1,
    const float* __restrict__ Wd2, const float* __restrict__ bd2,
    const float* __restrict__ Wp1, const float* __restrict__ bp1,
    const float* __restrict__ Wp2, const float* __restrict__ bp2,
    const float* __restrict__ Hprior, const float* __restrict__ Hpost,
    const float* __restrict__ Hp, const float* __restrict__ Diff,
    const float* __restrict__ MtM,
    float* __restrict__ z_state, float* __restrict__ out_z,
    float* __restrict__ loss_acc,
    int t0, int nt)
{
    int b  = blockIdx.x >> 1;
    int sh = blockIdx.x & 1;     // s = sh*4 + row
    int tid = threadIdx.x;

    __shared__ float zs[4][Z_DIM];
    __shared__ float ph[4][H_DIM];   // prior hidden; reused as p hidden
    __shared__ float qh[4][H_DIM];   // posterior hidden
    __shared__ float red2[256];

    for (int i = tid; i < 4 * Z_DIM; i += 256) {
        int r = i >> 7, j = i & 127;
        zs[r][j] = z_state[((size_t)b * S_DIM + sh * 4 + r) * Z_DIM + j];
    }
    float kacc = 0.f, racc = 0.f;
    const float* Wd1z = Wd1 + (size_t)R_DIM * H_DIM;
    const float* Wp1z = Wp1 + (size_t)R_DIM * H_DIM;
    __syncthreads();

    for (int tl = 0; tl < nt; ++tl) {
        int t = t0 + tl;
        size_t hbase = ((size_t)tl * B_DIM + b) * H_DIM;

        // -------- Phase A: ph/qh = relu(H{prior,post} + z @ Wd1z + bd1)
        {
            int c0 = tid, c1 = tid + 256;
            float acc0[4] = {0.f, 0.f, 0.f, 0.f};
            float acc1[4] = {0.f, 0.f, 0.f, 0.f};
            for (int k = 0; k < Z_DIM; k += 4) {
                float zv[4][4];
                #pragma unroll
                for (int r = 0; r < 4; ++r)
                    *(float4*)zv[r] = *(const float4*)&zs[r][k];
                #pragma unroll
                for (int kk = 0; kk < 4; ++kk) {
                    float w0 = Wd1z[(size_t)(k + kk) * H_DIM + c0];
                    float w1 = Wd1z[(size_t)(k + kk) * H_DIM + c1];
                    #pragma unroll
                    for (int r = 0; r < 4; ++r) {
                        acc0[r] = fmaf(zv[r][kk], w0, acc0[r]);
                        acc1[r] = fmaf(zv[r][kk], w1, acc1[r]);
                    }
                }
            }
            float hp0 = Hprior[hbase + c0] + bd1[c0];
            float hp1 = Hprior[hbase + c1] + bd1[c1];
            float hq0 = Hpost [hbase + c0] + bd1[c0];
            float hq1 = Hpost [hbase + c1] + bd1[c1];
            #pragma unroll
            for (int r = 0; r < 4; ++r) {
                ph[r][c0] = fmaxf(hp0 + acc0[r], 0.f);
                ph[r][c1] = fmaxf(hp1 + acc1[r], 0.f);
                qh[r][c0] = fmaxf(hq0 + acc0[r], 0.f);
                qh[r][c1] = fmaxf(hq1 + acc1[r], 0.f);
            }
        }
        __syncthreads();

        // -------- Phase B: prior/poster, z update, kld
        {
            int row = tid >> 6;
            int j0 = tid & 63, j1 = j0 + 64;
            float aP0 = 0.f, aP1 = 0.f, aQ0 = 0.f, aQ1 = 0.f;
            for (int h = 0; h < H_DIM; h += 4) {
                float pv[4], qv[4];
                *(float4*)pv = *(const float4*)&ph[row][h];
                *(float4*)qv = *(const float4*)&qh[row][h];
                #pragma unroll
                for (int hh = 0; hh < 4; ++hh) {
                    float w0 = Wd2[(size_t)(h + hh) * Z_DIM + j0];
                    float w1 = Wd2[(size_t)(h + hh) * Z_DIM + j1];
                    aP0 = fmaf(pv[hh], w0, aP0);
                    aP1 = fmaf(pv[hh], w1, aP1);
                    aQ0 = fmaf(qv[hh], w0, aQ0);
                    aQ1 = fmaf(qv[hh], w1, aQ1);
                }
            }
            int s = sh * 4 + row;
            size_t nbase = (((size_t)t * B_DIM + b) * S_DIM + s) * Z_DIM;
            size_t dbase = ((size_t)tl * B_DIM + b) * Z_DIM;
            {
                float prior  = 0.1f * tanh_fast(aP0 + bd2[j0]);
                float poster = 0.1f * tanh_fast(aQ0 + bd2[j0]);
                float dif = Diff[dbase + j0];
                float ep  = noise[nbase + j0];
                zs[row][j0] = zs[row][j0] + DT_F * poster + SQRT_DT_F * dif * ep;
                float e = (prior - poster) / dif;
                kacc = fmaf(e, e, kacc);
            }
            {
                float prior  = 0.1f * tanh_fast(aP1 + bd2[j1]);
                float poster = 0.1f * tanh_fast(aQ1 + bd2[j1]);
                float dif = Diff[dbase + j1];
                float ep  = noise[nbase + j1];
                zs[row][j1] = zs[row][j1] + DT_F * poster + SQRT_DT_F * dif * ep;
                float e = (prior - poster) / dif;
                kacc = fmaf(e, e, kacc);
            }
        }
        __syncthreads();

        // -------- Phase C: pw = relu(Hp + z_new @ Wp1z + bp1)  (into ph)
        {
            int c0 = tid, c1 = tid + 256;
            float acc0[4] = {0.f, 0.f, 0.f, 0.f};
            float acc1[4] = {0.f, 0.f, 0.f, 0.f};
            for (int k = 0; k < Z_DIM; k += 4) {
                float zv[4][4];
                #pragma unroll
                for (int r = 0; r < 4; ++r)
                    *(float4*)zv[r] = *(const float4*)&zs[r][k];
                #pragma unroll
                for (int kk = 0; kk < 4; ++kk) {
                    float w0 = Wp1z[(size_t)(k + kk) * H_DIM + c0];
                    float w1 = Wp1z[(size_t)(k + kk) * H_DIM + c1];
                    #pragma unroll
                    for (int r = 0; r < 4; ++r) {
                        acc0[r] = fmaf(zv[r][kk], w0, acc0[r]);
                        acc1[r] = fmaf(zv[r][kk], w1, acc1[r]);
                    }
                }
            }
            float hp0 = Hp[hbase + c0] + bp1[c0];
            float hp1 = Hp[hbase + c1] + bp1[c1];
            #pragma unroll
            for (int r = 0; r < 4; ++r) {
                ph[r][c0] = fmaxf(hp0 + acc0[r], 0.f);
                ph[r][c1] = fmaxf(hp1 + acc1[r], 0.f);
            }
        }
        __syncthreads();

        // -------- Phase D: p out, nll, recon
        {
            int row = tid >> 6;
            int d = tid & 63;
            float aM = 0.f, aL = 0.f;
            for (int h = 0; h < H_DIM; h += 4) {
                float pv[4];
                *(float4*)pv = *(const float4*)&ph[row][h];
                #pragma unroll
                for (int hh = 0; hh < 4; ++hh) {
                    float w1 = Wp2[(size_t)(h + hh) * (2 * DIN) + d];
                    float w2 = Wp2[(size_t)(h + hh) * (2 * DIN) + DIN + d];
                    aM = fmaf(pv[hh], w1, aM);
                    aL = fmaf(pv[hh], w2, aL);
                }
            }
            float mean = aM + bp2[d];
            float lv   = aL + bp2[DIN + d];
            float xv = X[((size_t)t * B_DIM + b) * DIN + d];
            float dm = xv - mean;
            float nll = 0.5f * (LOG_2PI_F + lv + dm * dm * __expf(-lv));
            racc = fmaf(MtM[(size_t)tl * B_DIM + b], nll, racc);
        }
        __syncthreads();
    }

    // write back z (ws for next chunk; out for final result — last chunk wins)
    for (int i = tid; i < 4 * Z_DIM; i += 256) {
        int r = i >> 7, j = i & 127;
        float zv = zs[r][j];
        size_t o = ((size_t)b * S_DIM + sh * 4 + r) * Z_DIM + j;
        z_state[o] = zv;
        out_z[o] = zv;
    }

    // block-reduce losses, one atomic each
    red2[tid] = kacc;
    __syncthreads();
    for (int st = 128; st > 0; st >>= 1) {
        if (tid < st) red2[tid] += red2[tid + st];
        __syncthreads();
    }
    if (tid == 0) atomicAdd(loss_acc + 0, red2[0]);
    __syncthreads();
    red2[tid] = racc;
    __syncthreads();
    for (int st = 128; st > 0; st >>= 1) {
        if (tid < st) red2[tid] += red2[tid + st];
        __syncthreads();
    }
    if (tid == 0) atomicAdd(loss_acc + 1, red2[0]);
}

// ---------------------------------------------------------------------------
// K3: finalize scalar losses
// ---------------------------------------------------------------------------
__global__ void k3_final(const float* __restrict__ loss_acc, float* __restrict__ out)
{
    if (threadIdx.x == 0 && blockIdx.x == 0) {
        float kld   = loss_acc[0] * (0.5f * DT_F / (float)(B_DIM * S_DIM));
        float recon = loss_acc[1] * (1.0f / (float)(B_DIM * S_DIM));
        out[131072] = recon + kld;   // loss_total (LAMBDA = 1)
        out[131073] = recon;         // loss_recon
        out[131074] = kld;           // loss_kld
    }
}

// ---------------------------------------------------------------------------
extern "C" void kernel_launch(void* const* d_in, const int* in_sizes, int n_in,
                              void* d_out, int out_size, void* d_ws, size_t ws_size,
                              hipStream_t stream)
{
    const float* X        = (const float*)d_in[0];
    const float* M        = (const float*)d_in[1];
    const float* cov      = (const float*)d_in[2];
    const float* path_h   = (const float*)d_in[3];
    const float* path_hpos= (const float*)d_in[4];
    const float* noise    = (const float*)d_in[5];
    const float* Wc1 = (const float*)d_in[6];
    const float* bc1 = (const float*)d_in[7];
    const float* Wc2 = (const float*)d_in[8];
    const float* bc2 = (const float*)d_in[9];
    const float* Wd1 = (const float*)d_in[10];
    const float* bd1 = (const float*)d_in[11];
    const float* Wd2 = (const float*)d_in[12];
    const float* bd2 = (const float*)d_in[13];
    const float* Wf1 = (const float*)d_in[14];
    const float* bf1 = (const float*)d_in[15];
    const float* Wf2 = (const float*)d_in[16];
    const float* bf2 = (const float*)d_in[17];
    const float* Wp1 = (const float*)d_in[18];
    const float* bp1 = (const float*)d_in[19];
    const float* Wp2 = (const float*)d_in[20];
    const float* bp2 = (const float*)d_in[21];
    float* out = (float*)d_out;

    // workspace layout (floats)
    float* ws = (float*)d_ws;
    float* z_state = ws;                          // 131072
    float* loss    = ws + 131072;                 // 2 (padded to 16)
    float* cbuf    = ws + 131072 + 16;

    const size_t per_t = (size_t)B_DIM * (3 * H_DIM + Z_DIM + 1);  // 213120 floats
    size_t avail = ws_size / sizeof(float);
    size_t fixed = 131072 + 16;
    int chunk = 1;
    if (avail > fixed) {
        size_t c = (avail - fixed) / per_t;
        chunk = (int)(c > 128 ? 128 : c);
        if (chunk < 1) chunk = 1;
        while (T_DIM % chunk) chunk--;
    }

    float* Hprior = cbuf;
    float* Hpost  = Hprior + (size_t)chunk * B_DIM * H_DIM;
    float* Hp     = Hpost  + (size_t)chunk * B_DIM * H_DIM;
    float* Diff   = Hp     + (size_t)chunk * B_DIM * H_DIM;
    float* MtM    = Diff   + (size_t)chunk * B_DIM * Z_DIM;

    k0_init<<<B_DIM, 128, 0, stream>>>(cov, Wc1, bc1, Wc2, bc2, z_state, loss);

    for (int t0 = 0; t0 < T_DIM; t0 += chunk) {
        k1_pre<<<chunk * 8, 256, 0, stream>>>(path_h, path_hpos, M,
                                              Wd1, Wf1, bf1, Wf2, bf2, Wp1,
                                              Hprior, Hpost, Hp, Diff, MtM, t0);
        k2_scan<<<256, 256, 0, stream>>>(X, noise,
                                         Wd1, bd1, Wd2, bd2, Wp1, bp1, Wp2, bp2,
                                         Hprior, Hpost, Hp, Diff, MtM,
                                         z_state, out, loss, t0, chunk);
    }

    k3_final<<<1, 64, 0, stream>>>(loss, out);
}

// Round 2
// 925.309 us; speedup vs baseline: 9.4895x; 9.4895x over previous
//
#include <hip/hip_runtime.h>
#include <hip/hip_bf16.h>
#include <math.h>

// Problem dims (fixed by setup_inputs)
#define T_DIM 128
#define B_DIM 128
#define S_DIM 8
#define DIN   64
#define R_DIM 256
#define Z_DIM 128
#define H_DIM 512
#define C_DIM 32
#define CH_DIM 64

#define DT_F      0.05f
#define SQRT_DT_F 0.22360679774997896f
#define LOG_2PI_F 1.8378770664093453f

typedef _Float16 f16;
typedef _Float16 f16x8 __attribute__((ext_vector_type(8)));
typedef float f32x4 __attribute__((ext_vector_type(4)));

union U16x8 { uint4 u; f16x8 h; };

__device__ __forceinline__ f32x4 mfma16(const uint4& a, const uint4& b, f32x4 c) {
    U16x8 ua, ub; ua.u = a; ub.u = b;
    return __builtin_amdgcn_mfma_f32_16x16x32_f16(ua.h, ub.h, c, 0, 0, 0);
}

__device__ __forceinline__ unsigned pk2(float a, float b) {
    unsigned short ua = __builtin_bit_cast(unsigned short, (f16)a);
    unsigned short ub = __builtin_bit_cast(unsigned short, (f16)b);
    return (unsigned)ua | ((unsigned)ub << 16);
}
__device__ __forceinline__ float upk_lo(unsigned u) {
    return (float)__builtin_bit_cast(f16, (unsigned short)(u & 0xffffu));
}
__device__ __forceinline__ float upk_hi(unsigned u) {
    return (float)__builtin_bit_cast(f16, (unsigned short)(u >> 16));
}

__device__ __forceinline__ float tanh_fast(float x) {
    float ax = fabsf(x);
    float e  = __expf(-2.0f * ax);
    float r  = (1.0f - e) / (1.0f + e);
    return copysignf(r, x);
}

// ---------------------------------------------------------------------------
// KW: pre-fragment weights into MFMA lane layouts (f16).
// A-frag (M-slice 16 x K-slice 32): elem(l,j) = W^T[m = base+(l&15)][k = 8*(l>>4)+j]
// 4 buffers x 65536 f16 each:
//   WA: Wd1z^T  tiles [w(8)][mt(4)][kt(4)]  (M=512, K=128)
//   WB: Wd2^T   tiles [jt(8)][kt(16)]       (M=128, K=512)
//   WC: Wp1z^T  like WA
//   WD: Wp2^T   like WB
// ---------------------------------------------------------------------------
__global__ __launch_bounds__(256) void kw_frag(
    const float* __restrict__ Wd1, const float* __restrict__ Wd2,
    const float* __restrict__ Wp1, const float* __restrict__ Wp2,
    f16* __restrict__ WA, f16* __restrict__ WB,
    f16* __restrict__ WC, f16* __restrict__ WD)
{
    int gid = blockIdx.x * 256 + threadIdx.x;       // [0, 262144)
    int buf = gid >> 16;
    int idx = gid & 65535;
    int j = idx & 7;
    int l = (idx >> 3) & 63;
    int tile = idx >> 9;                            // [0,128)
    int lr = l & 15, lg = l >> 4;
    float v;
    if (buf == 0 || buf == 2) {
        int w = tile >> 4, mt = (tile >> 2) & 3, kt = tile & 3;
        int c = w * 64 + mt * 16 + lr;              // H-column
        int k = kt * 32 + 8 * lg + j;               // z-row
        const float* W = (buf == 0) ? Wd1 : Wp1;
        v = W[(size_t)(R_DIM + k) * H_DIM + c];
    } else {
        int jt = tile >> 4, kt = tile & 15;
        int col = jt * 16 + lr;                     // out column
        int h = kt * 32 + 8 * lg + j;               // H-row
        const float* W = (buf == 1) ? Wd2 : Wp2;
        v = W[(size_t)h * Z_DIM + col];             // Z_DIM == 2*DIN == 128
    }
    f16* dst = (buf == 0) ? WA : (buf == 1) ? WB : (buf == 2) ? WC : WD;
    dst[idx] = (f16)v;
}

// ---------------------------------------------------------------------------
// K0: z0 = tanh(mlp(cov)); zero loss accumulators.
// ---------------------------------------------------------------------------
__global__ __launch_bounds__(128) void k0_init(
    const float* __restrict__ cov,
    const float* __restrict__ Wc1, const float* __restrict__ bc1,
    const float* __restrict__ Wc2, const float* __restrict__ bc2,
    float* __restrict__ z_state, float* __restrict__ loss_acc)
{
    int b = blockIdx.x;
    int tid = threadIdx.x;
    __shared__ float covs[C_DIM];
    __shared__ float hid[CH_DIM];
    if (tid < C_DIM) covs[tid] = cov[b * C_DIM + tid];
    __syncthreads();
    if (tid < CH_DIM) {
        float a = bc1[tid];
        #pragma unroll
        for (int c = 0; c < C_DIM; ++c) a = fmaf(covs[c], Wc1[c * CH_DIM + tid], a);
        hid[tid] = fmaxf(a, 0.0f);
    }
    __syncthreads();
    float a = bc2[tid];
    #pragma unroll 8
    for (int h = 0; h < CH_DIM; ++h) a = fmaf(hid[h], Wc2[h * Z_DIM + tid], a);
    float z0 = tanh_fast(a);
    #pragma unroll
    for (int s = 0; s < S_DIM; ++s)
        z_state[((size_t)b * S_DIM + s) * Z_DIM + tid] = z0;
    if (b == 0 && tid < 2) loss_acc[tid] = 0.0f;
}

// ---------------------------------------------------------------------------
// K1: precompute over all t (f32 compute, f16 outputs, biases folded):
//   HprF[t,b,:] = h @ Wd1[:R] + bd1
//   HpoF[t,b,:] = (h+hpos) @ Wd1[:R] + bd1
//   HpF [t,b,:] = h @ Wp1[:R] + bp1
//   Diff[t,b,:] = exp(relu(h@Wf1+bf1)@Wf2+bf2)   (f32)
//   MtM [t,b]   = mean(M[t,b,:])
// grid: 128*8 blocks (16 b per block, one t) x 256 threads
// ---------------------------------------------------------------------------
__global__ __launch_bounds__(256) void k1_pre(
    const float* __restrict__ path_h, const float* __restrict__ path_hpos,
    const float* __restrict__ M,
    const float* __restrict__ Wd1, const float* __restrict__ bd1,
    const float* __restrict__ Wf1, const float* __restrict__ bf1,
    const float* __restrict__ Wf2, const float* __restrict__ bf2,
    const float* __restrict__ Wp1, const float* __restrict__ bp1,
    f16* __restrict__ HprF, f16* __restrict__ HpoF, f16* __restrict__ HpF,
    float* __restrict__ Diff, float* __restrict__ MtM)
{
    int t  = blockIdx.x >> 3;
    int b0 = (blockIdx.x & 7) << 4;
    int tid = threadIdx.x;

    __shared__ float A [16][R_DIM];
    __shared__ float As[16][R_DIM];
    __shared__ float fh[16][H_DIM];
    __shared__ float red[256];

    {
        const float4* src  = (const float4*)(path_h    + ((size_t)t * B_DIM + b0) * R_DIM);
        const float4* srcp = (const float4*)(path_hpos + ((size_t)t * B_DIM + b0) * R_DIM);
        float4* Ad  = (float4*)&A[0][0];
        float4* Asd = (float4*)&As[0][0];
        for (int i = tid; i < 16 * R_DIM / 4; i += 256) {
            float4 v = src[i], vp = srcp[i];
            Ad[i] = v;
            Asd[i] = make_float4(v.x + vp.x, v.y + vp.y, v.z + vp.z, v.w + vp.w);
        }
    }
    __syncthreads();

    int r0 = (tid >> 6) << 2;
    int c0 = tid & 63;

    // ---- Hpr/Hpo
    {
        float accP[4][8], accQ[4][8];
        #pragma unroll
        for (int r = 0; r < 4; ++r)
            #pragma unroll
            for (int i = 0; i < 8; ++i) { accP[r][i] = 0.f; accQ[r][i] = 0.f; }
        for (int k = 0; k < R_DIM; k += 4) {
            float av[4][4], sv[4][4];
            #pragma unroll
            for (int r = 0; r < 4; ++r) {
                *(float4*)av[r] = *(const float4*)&A [r0 + r][k];
                *(float4*)sv[r] = *(const float4*)&As[r0 + r][k];
            }
            #pragma unroll
            for (int kk = 0; kk < 4; ++kk) {
                const float* wrow = Wd1 + (size_t)(k + kk) * H_DIM + c0;
                #pragma unroll
                for (int i = 0; i < 8; ++i) {
                    float w = wrow[i * 64];
                    #pragma unroll
                    for (int r = 0; r < 4; ++r) {
                        accP[r][i] = fmaf(av[r][kk], w, accP[r][i]);
                        accQ[r][i] = fmaf(sv[r][kk], w, accQ[r][i]);
                    }
                }
            }
        }
        #pragma unroll
        for (int i = 0; i < 8; ++i) {
            float bv = bd1[c0 + i * 64];
            #pragma unroll
            for (int r = 0; r < 4; ++r) {
                size_t o = ((size_t)t * B_DIM + b0 + r0 + r) * H_DIM + c0 + i * 64;
                HprF[o] = (f16)(accP[r][i] + bv);
                HpoF[o] = (f16)(accQ[r][i] + bv);
            }
        }
    }

    // ---- fh = relu(A @ Wf1 + bf1)
    {
        float accF[4][8];
        #pragma unroll
        for (int r = 0; r < 4; ++r)
            #pragma unroll
            for (int i = 0; i < 8; ++i) accF[r][i] = 0.f;
        for (int k = 0; k < R_DIM; k += 4) {
            float av[4][4];
            #pragma unroll
            for (int r = 0; r < 4; ++r)
                *(float4*)av[r] = *(const float4*)&A[r0 + r][k];
            #pragma unroll
            for (int kk = 0; kk < 4; ++kk) {
                const float* wrow = Wf1 + (size_t)(k + kk) * H_DIM + c0;
                #pragma unroll
                for (int i = 0; i < 8; ++i) {
                    float w = wrow[i * 64];
                    #pragma unroll
                    for (int r = 0; r < 4; ++r) accF[r][i] = fmaf(av[r][kk], w, accF[r][i]);
                }
            }
        }
        #pragma unroll
        for (int r = 0; r < 4; ++r)
            #pragma unroll
            for (int i = 0; i < 8; ++i)
                fh[r0 + r][c0 + i * 64] = fmaxf(accF[r][i] + bf1[c0 + i * 64], 0.f);
    }
    __syncthreads();

    // ---- Diff = exp(fh @ Wf2 + bf2)
    {
        int j  = tid & 127;
        int rg = (tid >> 7) << 3;
        float acc[8];
        #pragma unroll
        for (int r = 0; r < 8; ++r) acc[r] = 0.f;
        for (int h = 0; h < H_DIM; h += 4) {
            float fv[8][4];
            #pragma unroll
            for (int r = 0; r < 8; ++r)
                *(float4*)fv[r] = *(const float4*)&fh[rg + r][h];
            #pragma unroll
            for (int hh = 0; hh < 4; ++hh) {
                float w = Wf2[(size_t)(h + hh) * Z_DIM + j];
                #pragma unroll
                for (int r = 0; r < 8; ++r) acc[r] = fmaf(fv[r][hh], w, acc[r]);
            }
        }
        float bj = bf2[j];
        #pragma unroll
        for (int r = 0; r < 8; ++r)
            Diff[((size_t)t * B_DIM + b0 + rg + r) * Z_DIM + j] = __expf(acc[r] + bj);
    }

    // ---- HpF = A @ Wp1[:R] + bp1
    {
        float accH[4][8];
        #pragma unroll
        for (int r = 0; r < 4; ++r)
            #pragma unroll
            for (int i = 0; i < 8; ++i) accH[r][i] = 0.f;
        for (int k = 0; k < R_DIM; k += 4) {
            float av[4][4];
            #pragma unroll
            for (int r = 0; r < 4; ++r)
                *(float4*)av[r] = *(const float4*)&A[r0 + r][k];
            #pragma unroll
            for (int kk = 0; kk < 4; ++kk) {
                const float* wrow = Wp1 + (size_t)(k + kk) * H_DIM + c0;
                #pragma unroll
                for (int i = 0; i < 8; ++i) {
                    float w = wrow[i * 64];
                    #pragma unroll
                    for (int r = 0; r < 4; ++r) accH[r][i] = fmaf(av[r][kk], w, accH[r][i]);
                }
            }
        }
        #pragma unroll
        for (int i = 0; i < 8; ++i) {
            float bv = bp1[c0 + i * 64];
            #pragma unroll
            for (int r = 0; r < 4; ++r)
                HpF[((size_t)t * B_DIM + b0 + r0 + r) * H_DIM + c0 + i * 64] =
                    (f16)(accH[r][i] + bv);
        }
    }

    // ---- MtM
    {
        int row = tid >> 4, d0 = (tid & 15) << 2;
        float4 mv = *(const float4*)(M + ((size_t)t * B_DIM + b0 + row) * DIN + d0);
        red[tid] = mv.x + mv.y + mv.z + mv.w;
        __syncthreads();
        if ((tid & 15) == 0) {
            float s = 0.f;
            #pragma unroll
            for (int i = 0; i < 16; ++i) s += red[(row << 4) + i];
            MtM[(size_t)t * B_DIM + b0 + row] = s * (1.0f / 64.0f);
        }
    }
}

// ---------------------------------------------------------------------------
// K2: MFMA scan over t (phases A/B only). 256 blocks x 512 threads (8 waves).
// Block owns 4 rows: b = blk>>1, s = (blk&1)*4 + [0,4). N padded 4 -> 16.
// Weights live in VGPRs (pre-fragged):
//   wave wv: Wd1z^T M-rows [wv*64, wv*64+64)  (4 M-tiles x 4 K-tiles)
//            Wd2^T  M-rows [wv*16, wv*16+16)  (1 M-tile x 16 K-tiles)
// Per t:  G^T = Wd1z^T @ zh^T ; ph/qh = relu(G + Hpr/Hpo) -> frags
//         P/Q^T = Wd2^T @ {ph,qh}^T ; z += dt*poster + sqrt_dt*diff*eps ; kld
// Also writes z-trajectory (f16) for the recon kernel.
// ---------------------------------------------------------------------------
__global__ __launch_bounds__(512, 2) void k2_scan(
    const f16* __restrict__ WA, const f16* __restrict__ WB,
    const f16* __restrict__ HprF, const f16* __restrict__ HpoF,
    const float* __restrict__ Diff, const float* __restrict__ noise,
    const float* __restrict__ bd2,
    float* __restrict__ z_state, unsigned* __restrict__ ztraj_u,
    float* __restrict__ out_z, float* __restrict__ loss_acc)
{
    const int b  = blockIdx.x >> 1;
    const int sh = blockIdx.x & 1;
    const int tid = threadIdx.x;
    const int wv = tid >> 6, l = tid & 63;
    const int lr = l & 15, lg = l >> 4;

    __shared__ float zs[4][Z_DIM];          // 2 KB, f32 z state
    __shared__ uint4 zfrag[4][64];          // 4 KB,  B-frags of zh^T
    __shared__ uint4 phfrag[16][64];        // 16 KB, B-frags of ph^T
    __shared__ uint4 qhfrag[16][64];        // 16 KB
    __shared__ float red2[512];

    // ---- weights -> VGPR
    uint4 wa[4][4];
    #pragma unroll
    for (int mt = 0; mt < 4; ++mt)
        #pragma unroll
        for (int kt = 0; kt < 4; ++kt)
            wa[mt][kt] = ((const uint4*)(WA + (size_t)((wv * 4 + mt) * 4 + kt) * 512))[l];
    uint4 wb[16];
    #pragma unroll
    for (int kt = 0; kt < 16; ++kt)
        wb[kt] = ((const uint4*)(WB + (size_t)(wv * 16 + kt) * 512))[l];

    // ---- init z state
    if (tid < 512) {
        int r = tid >> 7, j = tid & 127;
        zs[r][j] = z_state[((size_t)b * S_DIM + sh * 4 + r) * Z_DIM + j];
    }
    __syncthreads();
    // initial zfrag
    if (tid < 256) {
        int kt = tid >> 6, ll = tid & 63;
        int n = ll & 15, kg = ll >> 4;
        uint4 u;
        if (n < 4) {
            const float* zp = &zs[n][kt * 32 + kg * 8];
            float4 a = *(const float4*)zp;
            float4 c = *(const float4*)(zp + 4);
            u.x = pk2(a.x, a.y); u.y = pk2(a.z, a.w);
            u.z = pk2(c.x, c.y); u.w = pk2(c.z, c.w);
        } else { u.x = u.y = u.z = u.w = 0u; }
        zfrag[kt][ll] = u;
    }
    __syncthreads();

    float kacc = 0.f;
    f16* phf = (f16*)phfrag;
    f16* qhf = (f16*)qhfrag;

    for (int t = 0; t < T_DIM; ++t) {
        const size_t hb = ((size_t)t * B_DIM + b) * H_DIM;

        // ---- phase A: G^T tiles, epilogue -> ph/qh frags
        uint4 zb[4];
        #pragma unroll
        for (int kt = 0; kt < 4; ++kt) zb[kt] = zfrag[kt][l];
        #pragma unroll
        for (int mt = 0; mt < 4; ++mt) {
            f32x4 acc = {0.f, 0.f, 0.f, 0.f};
            #pragma unroll
            for (int kt = 0; kt < 4; ++kt) acc = mfma16(wa[mt][kt], zb[kt], acc);
            int c0 = wv * 64 + mt * 16 + 4 * lg;    // H-column base (4 consecutive)
            uint2 hp = *(const uint2*)&HprF[hb + c0];
            uint2 hq = *(const uint2*)&HpoF[hb + c0];
            float p0 = fmaxf(acc[0] + upk_lo(hp.x), 0.f);
            float p1 = fmaxf(acc[1] + upk_hi(hp.x), 0.f);
            float p2 = fmaxf(acc[2] + upk_lo(hp.y), 0.f);
            float p3 = fmaxf(acc[3] + upk_hi(hp.y), 0.f);
            float q0 = fmaxf(acc[0] + upk_lo(hq.x), 0.f);
            float q1 = fmaxf(acc[1] + upk_hi(hq.x), 0.f);
            float q2 = fmaxf(acc[2] + upk_lo(hq.y), 0.f);
            float q3 = fmaxf(acc[3] + upk_hi(hq.y), 0.f);
            int ktp = c0 >> 5;
            int lp  = lr + 16 * ((c0 >> 3) & 3);
            int off = c0 & 7;                        // 0 or 4
            uint2 wp; wp.x = pk2(p0, p1); wp.y = pk2(p2, p3);
            uint2 wq; wq.x = pk2(q0, q1); wq.y = pk2(q2, q3);
            *(uint2*)&phf[(size_t)(ktp * 64 + lp) * 8 + off] = wp;
            *(uint2*)&qhf[(size_t)(ktp * 64 + lp) * 8 + off] = wq;
        }
        __syncthreads();

        // ---- phase B: P/Q^T, z update, kld
        {
            f32x4 aP = {0.f, 0.f, 0.f, 0.f};
            f32x4 aQ = {0.f, 0.f, 0.f, 0.f};
            #pragma unroll
            for (int kt = 0; kt < 16; ++kt) {
                uint4 pb = phfrag[kt][l];
                uint4 qb = qhfrag[kt][l];
                aP = mfma16(wb[kt], pb, aP);
                aQ = mfma16(wb[kt], qb, aQ);
            }
            if (lr < 4) {
                int r = lr, s = sh * 4 + r;
                int j0 = wv * 16 + 4 * lg;
                float4 dif = *(const float4*)&Diff[((size_t)t * B_DIM + b) * Z_DIM + j0];
                float4 ep  = *(const float4*)&noise[(((size_t)t * B_DIM + b) * S_DIM + s) * Z_DIM + j0];
                float4 b2  = *(const float4*)&bd2[j0];
                float4 zo  = *(const float4*)&zs[r][j0];
                float zn[4];
                #pragma unroll
                for (int i = 0; i < 4; ++i) {
                    float pr = 0.1f * tanh_fast(((const float*)&aP)[i] + ((const float*)&b2)[i]);
                    float po = 0.1f * tanh_fast(((const float*)&aQ)[i] + ((const float*)&b2)[i]);
                    float dv = ((const float*)&dif)[i];
                    zn[i] = ((const float*)&zo)[i] + DT_F * po
                          + SQRT_DT_F * dv * ((const float*)&ep)[i];
                    float e = (pr - po) / dv;
                    kacc = fmaf(e, e, kacc);
                }
                *(float4*)&zs[r][j0] = make_float4(zn[0], zn[1], zn[2], zn[3]);
            }
        }
        __syncthreads();

        // ---- z-traj write (f16) + zfrag repack
        if (tid < 256) {
            int r = tid >> 6, j2 = tid & 63;
            unsigned u = pk2(zs[r][2 * j2], zs[r][2 * j2 + 1]);
            ztraj_u[((size_t)t * 1024 + (size_t)b * 8 + sh * 4 + r) * 64 + j2] = u;
        }
        if (tid < 256) {
            int kt = tid >> 6, ll = tid & 63;
            int n = ll & 15, kg = ll >> 4;
            uint4 u;
            if (n < 4) {
                const float* zp = &zs[n][kt * 32 + kg * 8];
                float4 a = *(const float4*)zp;
                float4 c = *(const float4*)(zp + 4);
                u.x = pk2(a.x, a.y); u.y = pk2(a.z, a.w);
                u.z = pk2(c.x, c.y); u.w = pk2(c.z, c.w);
            } else { u.x = u.y = u.z = u.w = 0u; }
            zfrag[kt][ll] = u;
        }
        __syncthreads();
    }

    // ---- final z out
    if (tid < 512) {
        int r = tid >> 7, j = tid & 127;
        float zv = zs[r][j];
        size_t o = ((size_t)b * S_DIM + sh * 4 + r) * Z_DIM + j;
        z_state[o] = zv;
        out_z[o] = zv;
    }

    // ---- kld reduce
    red2[tid] = kacc;
    __syncthreads();
    for (int st = 256; st > 0; st >>= 1) {
        if (tid < st) red2[tid] += red2[tid + st];
        __syncthreads();
    }
    if (tid == 0) atomicAdd(loss_acc + 0, red2[0]);
}

// ---------------------------------------------------------------------------
// K3: recon (phases C/D), fully parallel over (t,b,s). 4096 blocks x 512 thr.
// Block: t = blk>>5, b0 = (blk&31)*4  -> 32 rows (4 b x 8 s), nt in [0,2).
//   pw = relu(HpF + z @ Wp1z)  (MFMA, transposed)  -> mean/logvar -> NLL
// ---------------------------------------------------------------------------
__global__ __launch_bounds__(512, 2) void k3_recon(
    const f16* __restrict__ WC, const f16* __restrict__ WD,
    const f16* __restrict__ HpF, const unsigned* __restrict__ ztraj_u,
    const float* __restrict__ X, const float* __restrict__ MtM,
    const float* __restrict__ bp2, float* __restrict__ loss_acc)
{
    const int t  = blockIdx.x >> 5;
    const int b0 = (blockIdx.x & 31) * 4;
    const int tid = threadIdx.x;
    const int wv = tid >> 6, l = tid & 63;
    const int lr = l & 15, lg = l >> 4;

    __shared__ uint4 zfrag[4][2][64];        // 8 KB
    __shared__ uint4 pwfrag[16][2][64];      // 32 KB
    __shared__ float obuf[128][33];          // ~16.9 KB
    __shared__ float red2[512];

    // ---- weights -> VGPR
    uint4 wc[4][4];
    #pragma unroll
    for (int mt = 0; mt < 4; ++mt)
        #pragma unroll
        for (int kt = 0; kt < 4; ++kt)
            wc[mt][kt] = ((const uint4*)(WC + (size_t)((wv * 4 + mt) * 4 + kt) * 512))[l];
    uint4 wd[16];
    #pragma unroll
    for (int kt = 0; kt < 16; ++kt)
        wd[kt] = ((const uint4*)(WD + (size_t)(wv * 16 + kt) * 512))[l];

    // ---- stage z frags from trajectory
    {
        int slot = tid;                      // [0,512) covers 4kt x 2nt x 64
        int kt = slot >> 7;
        int nt = (slot >> 6) & 1;
        int ll = slot & 63;
        int n = ll & 15, kg = ll >> 4;
        int rl = nt * 16 + n;                // row local [0,32)
        size_t grow = (size_t)t * 1024 + (size_t)b0 * 8 + rl;
        zfrag[kt][nt][ll] = *(const uint4*)&ztraj_u[grow * 64 + kt * 16 + kg * 4];
    }
    __syncthreads();

    // ---- P1: pw frags
    f16* pwf = (f16*)pwfrag;
    #pragma unroll
    for (int nt = 0; nt < 2; ++nt) {
        #pragma unroll
        for (int mt = 0; mt < 4; ++mt) {
            f32x4 acc = {0.f, 0.f, 0.f, 0.f};
            #pragma unroll
            for (int kt = 0; kt < 4; ++kt) acc = mfma16(wc[mt][kt], zfrag[kt][nt][l], acc);
            int c0 = wv * 64 + mt * 16 + 4 * lg;
            int rl = nt * 16 + lr;
            int bb = b0 + (rl >> 3);
            size_t hb = ((size_t)t * B_DIM + bb) * H_DIM;
            uint2 hp = *(const uint2*)&HpF[hb + c0];
            float p0 = fmaxf(acc[0] + upk_lo(hp.x), 0.f);
            float p1 = fmaxf(acc[1] + upk_hi(hp.x), 0.f);
            float p2 = fmaxf(acc[2] + upk_lo(hp.y), 0.f);
            float p3 = fmaxf(acc[3] + upk_hi(hp.y), 0.f);
            int ktp = c0 >> 5;
            int lp  = lr + 16 * ((c0 >> 3) & 3);
            int off = c0 & 7;
            uint2 wp; wp.x = pk2(p0, p1); wp.y = pk2(p2, p3);
            *(uint2*)&pwf[(size_t)((ktp * 2 + nt) * 64 + lp) * 8 + off] = wp;
        }
    }
    __syncthreads();

    // ---- P2: p outputs
    #pragma unroll
    for (int nt = 0; nt < 2; ++nt) {
        f32x4 acc = {0.f, 0.f, 0.f, 0.f};
        #pragma unroll
        for (int kt = 0; kt < 16; ++kt) acc = mfma16(wd[kt], pwfrag[kt][nt][l], acc);
        int m0 = wv * 16 + 4 * lg;
        int row = nt * 16 + lr;
        #pragma unroll
        for (int i = 0; i < 4; ++i) obuf[m0 + i][row] = acc[i];
    }
    __syncthreads();

    // ---- NLL
    float racc = 0.f;
    {
        int row = tid >> 4;                  // [0,32)
        int d4 = (tid & 15) * 4;
        int bb = b0 + (row >> 3);
        float mt = MtM[(size_t)t * B_DIM + bb];
        #pragma unroll
        for (int i = 0; i < 4; ++i) {
            int d = d4 + i;
            float mean = obuf[d][row] + bp2[d];
            float lv   = obuf[d + 64][row] + bp2[64 + d];
            float xv = X[((size_t)t * B_DIM + bb) * DIN + d];
            float dm = xv - mean;
            float nll = 0.5f * (LOG_2PI_F + lv + dm * dm * __expf(-lv));
            racc = fmaf(mt, nll, racc);
        }
    }
    red2[tid] = racc;
    __syncthreads();
    for (int st = 256; st > 0; st >>= 1) {
        if (tid < st) red2[tid] += red2[tid + st];
        __syncthreads();
    }
    if (tid == 0) atomicAdd(loss_acc + 1, red2[0]);
}

// ---------------------------------------------------------------------------
// K4: finalize
// ---------------------------------------------------------------------------
__global__ void k4_final(const float* __restrict__ loss_acc, float* __restrict__ out)
{
    if (threadIdx.x == 0 && blockIdx.x == 0) {
        float kld   = loss_acc[0] * (0.5f * DT_F / (float)(B_DIM * S_DIM));
        float recon = loss_acc[1] * (1.0f / (float)(B_DIM * S_DIM));
        out[131072] = recon + kld;
        out[131073] = recon;
        out[131074] = kld;
    }
}

// ---------------------------------------------------------------------------
extern "C" void kernel_launch(void* const* d_in, const int* in_sizes, int n_in,
                              void* d_out, int out_size, void* d_ws, size_t ws_size,
                              hipStream_t stream)
{
    const float* X        = (const float*)d_in[0];
    const float* M        = (const float*)d_in[1];
    const float* cov      = (const float*)d_in[2];
    const float* path_h   = (const float*)d_in[3];
    const float* path_hpos= (const float*)d_in[4];
    const float* noise    = (const float*)d_in[5];
    const float* Wc1 = (const float*)d_in[6];
    const float* bc1 = (const float*)d_in[7];
    const float* Wc2 = (const float*)d_in[8];
    const float* bc2 = (const float*)d_in[9];
    const float* Wd1 = (const float*)d_in[10];
    const float* bd1 = (const float*)d_in[11];
    const float* Wd2 = (const float*)d_in[12];
    const float* bd2 = (const float*)d_in[13];
    const float* Wf1 = (const float*)d_in[14];
    const float* bf1 = (const float*)d_in[15];
    const float* Wf2 = (const float*)d_in[16];
    const float* bf2 = (const float*)d_in[17];
    const float* Wp1 = (const float*)d_in[18];
    const float* bp1 = (const float*)d_in[19];
    const float* Wp2 = (const float*)d_in[20];
    const float* bp2 = (const float*)d_in[21];
    float* out = (float*)d_out;

    // workspace layout (bytes, 256-aligned)
    char* ws = (char*)d_ws;
    size_t o = 0;
    float* z_state = (float*)(ws + o); o += 524288;          // [1024][128] f32
    float* loss    = (float*)(ws + o); o += 256;
    f16* WA = (f16*)(ws + o); o += 131072;
    f16* WB = (f16*)(ws + o); o += 131072;
    f16* WC = (f16*)(ws + o); o += 131072;
    f16* WD = (f16*)(ws + o); o += 131072;
    f16* HprF = (f16*)(ws + o); o += 16777216;               // [T*B][512] f16
    f16* HpoF = (f16*)(ws + o); o += 16777216;
    f16* HpF  = (f16*)(ws + o); o += 16777216;
    float* Diff = (float*)(ws + o); o += 8388608;            // [T*B][128] f32
    float* MtM  = (float*)(ws + o); o += 65536;              // [T*B] f32
    unsigned* ztraj = (unsigned*)(ws + o); o += 33554432;    // [T*1024][64] f16x2

    kw_frag<<<1024, 256, 0, stream>>>(Wd1, Wd2, Wp1, Wp2, WA, WB, WC, WD);
    k0_init<<<B_DIM, 128, 0, stream>>>(cov, Wc1, bc1, Wc2, bc2, z_state, loss);
    k1_pre<<<T_DIM * 8, 256, 0, stream>>>(path_h, path_hpos, M,
                                          Wd1, bd1, Wf1, bf1, Wf2, bf2, Wp1, bp1,
                                          HprF, HpoF, HpF, Diff, MtM);
    k2_scan<<<256, 512, 0, stream>>>(WA, WB, HprF, HpoF, Diff, noise, bd2,
                                     z_state, ztraj, out, loss);
    k3_recon<<<4096, 512, 0, stream>>>(WC, WD, HpF, ztraj, X, MtM, bp2, loss);
    k4_final<<<1, 64, 0, stream>>>(loss, out);
}

// Round 4
// 679.136 us; speedup vs baseline: 12.9292x; 1.3625x over previous
//
#include <hip/hip_runtime.h>
#include <hip/hip_bf16.h>
#include <math.h>

// Problem dims (fixed by setup_inputs)
#define T_DIM 128
#define B_DIM 128
#define S_DIM 8
#define DIN   64
#define R_DIM 256
#define Z_DIM 128
#define H_DIM 512
#define C_DIM 32
#define CH_DIM 64

#define DT_F      0.05f
#define SQRT_DT_F 0.22360679774997896f
#define LOG_2PI_F 1.8378770664093453f

typedef _Float16 f16;
typedef __fp16 fp16x2 __attribute__((ext_vector_type(2)));
typedef _Float16 f16x8 __attribute__((ext_vector_type(8)));
typedef float f32x4 __attribute__((ext_vector_type(4)));

union U16x8 { uint4 u; f16x8 h; };

__device__ __forceinline__ f32x4 mfma16(const uint4& a, const uint4& b, f32x4 c) {
    U16x8 ua, ub; ua.u = a; ub.u = b;
    return __builtin_amdgcn_mfma_f32_16x16x32_f16(ua.h, ub.h, c, 0, 0, 0);
}

__device__ __forceinline__ unsigned pk2(float a, float b) {
    fp16x2 h = __builtin_amdgcn_cvt_pkrtz(a, b);
    return __builtin_bit_cast(unsigned, h);
}
__device__ __forceinline__ float upk_lo(unsigned u) {
    return (float)__builtin_bit_cast(f16, (unsigned short)(u & 0xffffu));
}
__device__ __forceinline__ float upk_hi(unsigned u) {
    return (float)__builtin_bit_cast(f16, (unsigned short)(u >> 16));
}

__device__ __forceinline__ float tanh_fast(float x) {
    float ax = fabsf(x);
    float e  = __expf(-2.0f * ax);
    float r  = (1.0f - e) / (1.0f + e);
    return copysignf(r, x);
}

// ---------------------------------------------------------------------------
// KW: pre-fragment weights into MFMA A-frag layouts (f16).
// A-frag elem(l,j) of tile (mt,kt): W[k0 + kt*32 + 8*(l>>4) + j][mt*16 + (l&15)]
// tile index = mt*NKT + kt.
// Buffers (64K f16 units):
//   [0]    WA  : Wd1z^T  M=512 K=128 (NKT=4)
//   [1]    WB  : Wd2^T   M=128 K=512 (NKT=16)
//   [2]    WC  : Wp1z^T  M=512 K=128 (NKT=4)
//   [3]    WD  : Wp2^T   M=128 K=512 (NKT=16)
//   [4,5]  W1A : Wd1[:R]^T M=512 K=256 (NKT=8)
//   [6,7]  WF1 : Wf1^T   M=512 K=256 (NKT=8)
//   [8,9]  WP1A: Wp1[:R]^T M=512 K=256 (NKT=8)
//   [10]   WF2 : Wf2^T   M=128 K=512 (NKT=16)
// ---------------------------------------------------------------------------
__global__ __launch_bounds__(256) void kw_frag(
    const float* __restrict__ Wd1, const float* __restrict__ Wd2,
    const float* __restrict__ Wp1, const float* __restrict__ Wp2,
    const float* __restrict__ Wf1, const float* __restrict__ Wf2,
    f16* __restrict__ WA, f16* __restrict__ WB,
    f16* __restrict__ WC, f16* __restrict__ WD,
    f16* __restrict__ W1A, f16* __restrict__ WF1,
    f16* __restrict__ WP1A, f16* __restrict__ WF2)
{
    int gid = blockIdx.x * 256 + threadIdx.x;    // [0, 720896)
    const float* W; f16* dst; int k0, nktl, ld, off;
    if      (gid < 65536)  { W = Wd1; dst = WA;   k0 = 256; nktl = 2; ld = 512; off = gid; }
    else if (gid < 131072) { W = Wd2; dst = WB;   k0 = 0;   nktl = 4; ld = 128; off = gid - 65536; }
    else if (gid < 196608) { W = Wp1; dst = WC;   k0 = 256; nktl = 2; ld = 512; off = gid - 131072; }
    else if (gid < 262144) { W = Wp2; dst = WD;   k0 = 0;   nktl = 4; ld = 128; off = gid - 196608; }
    else if (gid < 393216) { W = Wd1; dst = W1A;  k0 = 0;   nktl = 3; ld = 512; off = gid - 262144; }
    else if (gid < 524288) { W = Wf1; dst = WF1;  k0 = 0;   nktl = 3; ld = 512; off = gid - 393216; }
    else if (gid < 655360) { W = Wp1; dst = WP1A; k0 = 0;   nktl = 3; ld = 512; off = gid - 524288; }
    else                   { W = Wf2; dst = WF2;  k0 = 0;   nktl = 4; ld = 128; off = gid - 655360; }
    int j = off & 7, l = (off >> 3) & 63, tile = off >> 9;
    int mt = tile >> nktl, kt = tile & ((1 << nktl) - 1);
    int lr = l & 15, lg = l >> 4;
    int c = mt * 16 + lr;
    int k = k0 + kt * 32 + 8 * lg + j;
    dst[off] = (f16)W[(size_t)k * ld + c];
}

// ---------------------------------------------------------------------------
// K0: z0 = tanh(mlp(cov)); zero loss accumulators.
// ---------------------------------------------------------------------------
__global__ __launch_bounds__(128) void k0_init(
    const float* __restrict__ cov,
    const float* __restrict__ Wc1, const float* __restrict__ bc1,
    const float* __restrict__ Wc2, const float* __restrict__ bc2,
    float* __restrict__ z_state, float* __restrict__ loss_acc)
{
    int b = blockIdx.x;
    int tid = threadIdx.x;
    __shared__ float covs[C_DIM];
    __shared__ float hid[CH_DIM];
    if (tid < C_DIM) covs[tid] = cov[b * C_DIM + tid];
    __syncthreads();
    if (tid < CH_DIM) {
        float a = bc1[tid];
        #pragma unroll
        for (int c = 0; c < C_DIM; ++c) a = fmaf(covs[c], Wc1[c * CH_DIM + tid], a);
        hid[tid] = fmaxf(a, 0.0f);
    }
    __syncthreads();
    float a = bc2[tid];
    #pragma unroll 8
    for (int h = 0; h < CH_DIM; ++h) a = fmaf(hid[h], Wc2[h * Z_DIM + tid], a);
    float z0 = tanh_fast(a);
    #pragma unroll
    for (int s = 0; s < S_DIM; ++s)
        z_state[((size_t)b * S_DIM + s) * Z_DIM + tid] = z0;
    if (b == 0 && tid < 2) loss_acc[tid] = 0.0f;
}

// ---------------------------------------------------------------------------
// K1 (MFMA): per block 64 rows (row = t*128+b), 8 waves.
//   HprF = h@Wd1[:R]+bd1, HpoF = (h+hpos)@Wd1[:R]+bd1, HpF = h@Wp1[:R]+bp1 (f16)
//   Diff = exp(relu(h@Wf1+bf1)@Wf2+bf2) (f32), MtM = mean(M) per row.
// Weights streamed from pre-fragged L2 buffers; rows built as B-frags in LDS.
// ---------------------------------------------------------------------------
__global__ __launch_bounds__(512, 1) void k1_pre(
    const float* __restrict__ path_h, const float* __restrict__ path_hpos,
    const float* __restrict__ M,
    const f16* __restrict__ W1A, const f16* __restrict__ WF1,
    const f16* __restrict__ WP1A, const f16* __restrict__ WF2,
    const float* __restrict__ bd1, const float* __restrict__ bf1,
    const float* __restrict__ bf2, const float* __restrict__ bp1,
    f16* __restrict__ HprF, f16* __restrict__ HpoF, f16* __restrict__ HpF,
    float* __restrict__ Diff, float* __restrict__ MtM)
{
    const int base = blockIdx.x * 64;
    const int tid = threadIdx.x;
    const int wv = tid >> 6, l = tid & 63;
    const int lr = l & 15, lg = l >> 4;

    __shared__ uint4 ABf[2][4][8][64];   // 64 KB: [arr][nt][kt][lane]
    __shared__ uint4 FHf[4][16][64];     // 64 KB: fh frags [nt][kt][lane]

    // ---- MtM (independent of LDS)
    {
        int row = base + (tid >> 3), sg = tid & 7;
        const float4* mp = (const float4*)(M + (size_t)row * DIN + sg * 8);
        float4 m0 = mp[0], m1 = mp[1];
        float sm = m0.x + m0.y + m0.z + m0.w + m1.x + m1.y + m1.z + m1.w;
        sm += __shfl_xor(sm, 1);
        sm += __shfl_xor(sm, 2);
        sm += __shfl_xor(sm, 4);
        if (sg == 0) MtM[row] = sm * (1.0f / 64.0f);
    }

    // ---- stage rows as B-frags (A and A+hpos)
    for (int it = 0; it < 4; ++it) {
        int s = it * 512 + tid;               // [0,2048)
        int ktkg = s & 31, n = (s >> 5) & 15, nt = s >> 9;
        int kt = ktkg >> 2, kg = ktkg & 3;
        int row = base + nt * 16 + n;
        const float4* ph4 = (const float4*)(path_h    + (size_t)row * R_DIM + kt * 32 + kg * 8);
        const float4* pp4 = (const float4*)(path_hpos + (size_t)row * R_DIM + kt * 32 + kg * 8);
        float4 a0 = ph4[0], a1 = ph4[1];
        float4 p0 = pp4[0], p1 = pp4[1];
        uint4 ua, us;
        ua.x = pk2(a0.x, a0.y); ua.y = pk2(a0.z, a0.w);
        ua.z = pk2(a1.x, a1.y); ua.w = pk2(a1.z, a1.w);
        us.x = pk2(a0.x + p0.x, a0.y + p0.y); us.y = pk2(a0.z + p0.z, a0.w + p0.w);
        us.z = pk2(a1.x + p1.x, a1.y + p1.y); us.w = pk2(a1.z + p1.z, a1.w + p1.w);
        int ll = n + 16 * kg;
        ABf[0][nt][kt][ll] = ua;
        ABf[1][nt][kt][ll] = us;
    }
    __syncthreads();

    // ---- GEMM1: Hpr & Hpo (share weights W1A)
    {
        f32x4 accP[4][4], accQ[4][4];
        #pragma unroll
        for (int mt = 0; mt < 4; ++mt)
            #pragma unroll
            for (int nt = 0; nt < 4; ++nt) { accP[mt][nt] = (f32x4)0.f; accQ[mt][nt] = (f32x4)0.f; }
        for (int kt = 0; kt < 8; ++kt) {
            uint4 wa[4], bA[4], bS[4];
            #pragma unroll
            for (int mt = 0; mt < 4; ++mt)
                wa[mt] = ((const uint4*)W1A)[(size_t)((wv * 4 + mt) * 8 + kt) * 64 + l];
            #pragma unroll
            for (int nt = 0; nt < 4; ++nt) { bA[nt] = ABf[0][nt][kt][l]; bS[nt] = ABf[1][nt][kt][l]; }
            #pragma unroll
            for (int mt = 0; mt < 4; ++mt)
                #pragma unroll
                for (int nt = 0; nt < 4; ++nt) {
                    accP[mt][nt] = mfma16(wa[mt], bA[nt], accP[mt][nt]);
                    accQ[mt][nt] = mfma16(wa[mt], bS[nt], accQ[mt][nt]);
                }
        }
        #pragma unroll
        for (int mt = 0; mt < 4; ++mt) {
            int c0 = wv * 64 + mt * 16 + 4 * lg;
            float4 bv = *(const float4*)&bd1[c0];
            #pragma unroll
            for (int nt = 0; nt < 4; ++nt) {
                size_t o = (size_t)(base + nt * 16 + lr) * H_DIM + c0;
                uint2 wp, wq;
                wp.x = pk2(accP[mt][nt][0] + bv.x, accP[mt][nt][1] + bv.y);
                wp.y = pk2(accP[mt][nt][2] + bv.z, accP[mt][nt][3] + bv.w);
                wq.x = pk2(accQ[mt][nt][0] + bv.x, accQ[mt][nt][1] + bv.y);
                wq.y = pk2(accQ[mt][nt][2] + bv.z, accQ[mt][nt][3] + bv.w);
                *(uint2*)&HprF[o] = wp;
                *(uint2*)&HpoF[o] = wq;
            }
        }
    }

    // ---- GEMM2: Hp
    {
        f32x4 accH[4][4];
        #pragma unroll
        for (int mt = 0; mt < 4; ++mt)
            #pragma unroll
            for (int nt = 0; nt < 4; ++nt) accH[mt][nt] = (f32x4)0.f;
        for (int kt = 0; kt < 8; ++kt) {
            uint4 wa[4], bA[4];
            #pragma unroll
            for (int mt = 0; mt < 4; ++mt)
                wa[mt] = ((const uint4*)WP1A)[(size_t)((wv * 4 + mt) * 8 + kt) * 64 + l];
            #pragma unroll
            for (int nt = 0; nt < 4; ++nt) bA[nt] = ABf[0][nt][kt][l];
            #pragma unroll
            for (int mt = 0; mt < 4; ++mt)
                #pragma unroll
                for (int nt = 0; nt < 4; ++nt) accH[mt][nt] = mfma16(wa[mt], bA[nt], accH[mt][nt]);
        }
        #pragma unroll
        for (int mt = 0; mt < 4; ++mt) {
            int c0 = wv * 64 + mt * 16 + 4 * lg;
            float4 bv = *(const float4*)&bp1[c0];
            #pragma unroll
            for (int nt = 0; nt < 4; ++nt) {
                size_t o = (size_t)(base + nt * 16 + lr) * H_DIM + c0;
                uint2 wp;
                wp.x = pk2(accH[mt][nt][0] + bv.x, accH[mt][nt][1] + bv.y);
                wp.y = pk2(accH[mt][nt][2] + bv.z, accH[mt][nt][3] + bv.w);
                *(uint2*)&HpF[o] = wp;
            }
        }
    }

    // ---- GEMM3: fh = relu(A@Wf1+bf1) -> FHf frags
    {
        f32x4 accF[4][4];
        #pragma unroll
        for (int mt = 0; mt < 4; ++mt)
            #pragma unroll
            for (int nt = 0; nt < 4; ++nt) accF[mt][nt] = (f32x4)0.f;
        for (int kt = 0; kt < 8; ++kt) {
            uint4 wa[4], bA[4];
            #pragma unroll
            for (int mt = 0; mt < 4; ++mt)
                wa[mt] = ((const uint4*)WF1)[(size_t)((wv * 4 + mt) * 8 + kt) * 64 + l];
            #pragma unroll
            for (int nt = 0; nt < 4; ++nt) bA[nt] = ABf[0][nt][kt][l];
            #pragma unroll
            for (int mt = 0; mt < 4; ++mt)
                #pragma unroll
                for (int nt = 0; nt < 4; ++nt) accF[mt][nt] = mfma16(wa[mt], bA[nt], accF[mt][nt]);
        }
        #pragma unroll
        for (int mt = 0; mt < 4; ++mt) {
            int c0 = wv * 64 + mt * 16 + 4 * lg;
            float4 bv = *(const float4*)&bf1[c0];
            int kt2 = c0 >> 5;
            int l2  = lr + 16 * ((c0 >> 3) & 3);
            int half = (c0 & 7) >> 2;
            #pragma unroll
            for (int nt = 0; nt < 4; ++nt) {
                uint2 wp;
                wp.x = pk2(fmaxf(accF[mt][nt][0] + bv.x, 0.f), fmaxf(accF[mt][nt][1] + bv.y, 0.f));
                wp.y = pk2(fmaxf(accF[mt][nt][2] + bv.z, 0.f), fmaxf(accF[mt][nt][3] + bv.w, 0.f));
                ((uint2*)&FHf[nt][kt2][l2])[half] = wp;
            }
        }
    }
    __syncthreads();

    // ---- GEMM4: Diff = exp(fh@Wf2+bf2); wave wv owns 16 output cols
    {
        f32x4 accD[4];
        #pragma unroll
        for (int nt = 0; nt < 4; ++nt) accD[nt] = (f32x4)0.f;
        for (int kt = 0; kt < 16; ++kt) {
            uint4 wf = ((const uint4*)WF2)[(size_t)(wv * 16 + kt) * 64 + l];
            #pragma unroll
            for (int nt = 0; nt < 4; ++nt) accD[nt] = mfma16(wf, FHf[nt][kt][l], accD[nt]);
        }
        int c0 = wv * 16 + 4 * lg;
        float4 bv = *(const float4*)&bf2[c0];
        #pragma unroll
        for (int nt = 0; nt < 4; ++nt) {
            float4 o;
            o.x = __expf(accD[nt][0] + bv.x);
            o.y = __expf(accD[nt][1] + bv.y);
            o.z = __expf(accD[nt][2] + bv.z);
            o.w = __expf(accD[nt][3] + bv.w);
            *(float4*)&Diff[(size_t)(base + nt * 16 + lr) * Z_DIM + c0] = o;
        }
    }
}

// ---------------------------------------------------------------------------
// K2: MFMA scan (phases A/B). 256 blocks x 512 threads (8 waves).
// Block owns 4 rows: b = blk>>1, s = (blk&1)*4 + lr (lr<4 lanes = "owners").
// All frag traffic exec-masked to the 16 real columns; z lives in owner regs.
// 2 barriers per t.
// ---------------------------------------------------------------------------
__global__ __launch_bounds__(512, 1) void k2_scan(
    const f16* __restrict__ WA, const f16* __restrict__ WB,
    const f16* __restrict__ HprF, const f16* __restrict__ HpoF,
    const float* __restrict__ Diff, const float* __restrict__ noise,
    const float* __restrict__ bd2,
    const float* __restrict__ z_state, unsigned* __restrict__ ztraj_u,
    float* __restrict__ out_z, float* __restrict__ loss_acc)
{
    const int b  = blockIdx.x >> 1;
    const int sh = blockIdx.x & 1;
    const int tid = threadIdx.x;
    const int wv = tid >> 6, l = tid & 63;
    const int lr = l & 15, lg = l >> 4;
    const bool owner = (lr < 4);

    __shared__ uint4 zfrag[4][64];          // 4 KB
    __shared__ uint4 phfrag[16][64];        // 16 KB
    __shared__ uint4 qhfrag[16][64];        // 16 KB
    __shared__ float red2[512];

    // ---- weights -> VGPR
    uint4 wa[4][4];
    #pragma unroll
    for (int mt = 0; mt < 4; ++mt)
        #pragma unroll
        for (int kt = 0; kt < 4; ++kt)
            wa[mt][kt] = ((const uint4*)WA)[(size_t)((wv * 4 + mt) * 4 + kt) * 64 + l];
    uint4 wb[16];
    #pragma unroll
    for (int kt = 0; kt < 16; ++kt)
        wb[kt] = ((const uint4*)WB)[(size_t)(wv * 16 + kt) * 64 + l];

    // ---- owner state
    const int j0 = wv * 16 + 4 * lg;        // z columns [j0, j0+4)
    const int srow = sh * 4 + lr;           // s index (owners)
    float zreg[4] = {0.f, 0.f, 0.f, 0.f};
    float bdv[4] = {0.f, 0.f, 0.f, 0.f};
    uint2* zslot = ((uint2*)&zfrag[wv >> 1][lr + 16 * (2 * (wv & 1) + (lg >> 1))]) + (lg & 1);
    if (owner) {
        *(float4*)zreg = *(const float4*)&z_state[((size_t)b * S_DIM + srow) * Z_DIM + j0];
        *(float4*)bdv  = *(const float4*)&bd2[j0];
        uint2 zz; zz.x = pk2(zreg[0], zreg[1]); zz.y = pk2(zreg[2], zreg[3]);
        *zslot = zz;
    }
    __syncthreads();

    float kacc = 0.f;

    for (int t = 0; t < T_DIM; ++t) {
        const size_t hb = ((size_t)t * B_DIM + b) * H_DIM;

        // -------- phase A: G^T = Wd1z^T @ z^T, epilogue -> ph/qh frags
        uint4 zb[4];
        #pragma unroll
        for (int kt = 0; kt < 4; ++kt) zb[kt] = make_uint4(0u, 0u, 0u, 0u);
        uint2 hp[4], hq[4];
        if (owner) {
            #pragma unroll
            for (int kt = 0; kt < 4; ++kt) zb[kt] = zfrag[kt][l];
            #pragma unroll
            for (int mt = 0; mt < 4; ++mt) {
                int c0 = wv * 64 + mt * 16 + 4 * lg;
                hp[mt] = *(const uint2*)&HprF[hb + c0];
                hq[mt] = *(const uint2*)&HpoF[hb + c0];
            }
        }
        #pragma unroll
        for (int mt = 0; mt < 4; ++mt) {
            f32x4 acc = (f32x4)0.f;
            #pragma unroll
            for (int kt = 0; kt < 4; ++kt) acc = mfma16(wa[mt][kt], zb[kt], acc);
            if (owner) {
                fp16x2 zero2 = {(__fp16)0.f, (__fp16)0.f};
                fp16x2 a01 = __builtin_amdgcn_cvt_pkrtz(acc[0], acc[1]);
                fp16x2 a23 = __builtin_amdgcn_cvt_pkrtz(acc[2], acc[3]);
                fp16x2 p01 = __builtin_elementwise_max(a01 + __builtin_bit_cast(fp16x2, hp[mt].x), zero2);
                fp16x2 p23 = __builtin_elementwise_max(a23 + __builtin_bit_cast(fp16x2, hp[mt].y), zero2);
                fp16x2 q01 = __builtin_elementwise_max(a01 + __builtin_bit_cast(fp16x2, hq[mt].x), zero2);
                fp16x2 q23 = __builtin_elementwise_max(a23 + __builtin_bit_cast(fp16x2, hq[mt].y), zero2);
                int c0 = wv * 64 + mt * 16 + 4 * lg;
                int ktp = c0 >> 5;
                int l2  = lr + 16 * ((c0 >> 3) & 3);
                int half = (c0 & 7) >> 2;
                uint2 wp, wq;
                wp.x = __builtin_bit_cast(unsigned, p01); wp.y = __builtin_bit_cast(unsigned, p23);
                wq.x = __builtin_bit_cast(unsigned, q01); wq.y = __builtin_bit_cast(unsigned, q23);
                ((uint2*)&phfrag[ktp][l2])[half] = wp;
                ((uint2*)&qhfrag[ktp][l2])[half] = wq;
            }
        }
        __syncthreads();

        // -------- phase B: P/Q^T = Wd2^T @ {ph,qh}^T; z update; kld
        f32x4 aP = (f32x4)0.f, aQ = (f32x4)0.f;
        #pragma unroll
        for (int kt = 0; kt < 16; ++kt) {
            uint4 pb = make_uint4(0u, 0u, 0u, 0u);
            uint4 qb = make_uint4(0u, 0u, 0u, 0u);
            if (owner) { pb = phfrag[kt][l]; qb = qhfrag[kt][l]; }
            aP = mfma16(wb[kt], pb, aP);
            aQ = mfma16(wb[kt], qb, aQ);
        }
        if (owner) {
            float4 dif = *(const float4*)&Diff[((size_t)t * B_DIM + b) * Z_DIM + j0];
            float4 ep  = *(const float4*)&noise[(((size_t)t * B_DIM + b) * S_DIM + srow) * Z_DIM + j0];
            const float* difp = (const float*)&dif;
            const float* epp  = (const float*)&ep;
            #pragma unroll
            for (int i = 0; i < 4; ++i) {
                float pr = 0.1f * tanh_fast(aP[i] + bdv[i]);
                float po = 0.1f * tanh_fast(aQ[i] + bdv[i]);
                float dv = difp[i];
                zreg[i] = zreg[i] + DT_F * po + SQRT_DT_F * dv * epp[i];
                float e = (pr - po) / dv;
                kacc = fmaf(e, e, kacc);
            }
            uint2 zz; zz.x = pk2(zreg[0], zreg[1]); zz.y = pk2(zreg[2], zreg[3]);
            *zslot = zz;
            *(uint2*)&ztraj_u[((size_t)t * 1024 + (size_t)b * S_DIM + srow) * 64 + (j0 >> 1)] = zz;
        }
        __syncthreads();
    }

    // ---- final z out
    if (owner)
        *(float4*)&out_z[((size_t)b * S_DIM + srow) * Z_DIM + j0] = *(const float4*)zreg;

    // ---- kld reduce
    red2[tid] = kacc;
    __syncthreads();
    for (int st = 256; st > 0; st >>= 1) {
        if (tid < st) red2[tid] += red2[tid + st];
        __syncthreads();
    }
    if (tid == 0) atomicAdd(loss_acc + 0, red2[0]);
}

// ---------------------------------------------------------------------------
// K3: recon (phases C/D), fully parallel over (t,b,s). 4096 blocks x 512 thr.
// ---------------------------------------------------------------------------
__global__ __launch_bounds__(512, 2) void k3_recon(
    const f16* __restrict__ WC, const f16* __restrict__ WD,
    const f16* __restrict__ HpF, const unsigned* __restrict__ ztraj_u,
    const float* __restrict__ X, const float* __restrict__ MtM,
    const float* __restrict__ bp2, float* __restrict__ loss_acc)
{
    const int t  = blockIdx.x >> 5;
    const int b0 = (blockIdx.x & 31) * 4;
    const int tid = threadIdx.x;
    const int wv = tid >> 6, l = tid & 63;
    const int lr = l & 15, lg = l >> 4;

    __shared__ uint4 zfrag[4][2][64];        // 8 KB
    __shared__ uint4 pwfrag[16][2][64];      // 32 KB
    __shared__ float obuf[128][33];          // ~16.9 KB
    __shared__ float red2[512];

    // ---- weights -> VGPR
    uint4 wc[4][4];
    #pragma unroll
    for (int mt = 0; mt < 4; ++mt)
        #pragma unroll
        for (int kt = 0; kt < 4; ++kt)
            wc[mt][kt] = ((const uint4*)WC)[(size_t)((wv * 4 + mt) * 4 + kt) * 64 + l];
    uint4 wd[16];
    #pragma unroll
    for (int kt = 0; kt < 16; ++kt)
        wd[kt] = ((const uint4*)WD)[(size_t)(wv * 16 + kt) * 64 + l];

    // ---- stage z frags from trajectory
    {
        int kt = tid >> 7;
        int nt = (tid >> 6) & 1;
        int ll = tid & 63;
        int n = ll & 15, kg = ll >> 4;
        int rl = nt * 16 + n;
        size_t grow = (size_t)t * 1024 + (size_t)b0 * S_DIM + rl;
        zfrag[kt][nt][ll] = *(const uint4*)&ztraj_u[grow * 64 + kt * 16 + kg * 4];
    }
    __syncthreads();

    // ---- P1: pw frags
    f16* pwf = (f16*)pwfrag;
    #pragma unroll
    for (int nt = 0; nt < 2; ++nt) {
        #pragma unroll
        for (int mt = 0; mt < 4; ++mt) {
            f32x4 acc = (f32x4)0.f;
            #pragma unroll
            for (int kt = 0; kt < 4; ++kt) acc = mfma16(wc[mt][kt], zfrag[kt][nt][l], acc);
            int c0 = wv * 64 + mt * 16 + 4 * lg;
            int rl = nt * 16 + lr;
            int bb = b0 + (rl >> 3);
            size_t hbs = ((size_t)t * B_DIM + bb) * H_DIM;
            uint2 hpv = *(const uint2*)&HpF[hbs + c0];
            float p0 = fmaxf(acc[0] + upk_lo(hpv.x), 0.f);
            float p1 = fmaxf(acc[1] + upk_hi(hpv.x), 0.f);
            float p2 = fmaxf(acc[2] + upk_lo(hpv.y), 0.f);
            float p3 = fmaxf(acc[3] + upk_hi(hpv.y), 0.f);
            int ktp = c0 >> 5;
            int lp  = lr + 16 * ((c0 >> 3) & 3);
            int off = c0 & 7;
            uint2 wp; wp.x = pk2(p0, p1); wp.y = pk2(p2, p3);
            *(uint2*)&pwf[(size_t)((ktp * 2 + nt) * 64 + lp) * 8 + off] = wp;
        }
    }
    __syncthreads();

    // ---- P2: p outputs
    #pragma unroll
    for (int nt = 0; nt < 2; ++nt) {
        f32x4 acc = (f32x4)0.f;
        #pragma unroll
        for (int kt = 0; kt < 16; ++kt) acc = mfma16(wd[kt], pwfrag[kt][nt][l], acc);
        int m0 = wv * 16 + 4 * lg;
        int row = nt * 16 + lr;
        #pragma unroll
        for (int i = 0; i < 4; ++i) obuf[m0 + i][row] = acc[i];
    }
    __syncthreads();

    // ---- NLL
    float racc = 0.f;
    {
        int row = tid >> 4;
        int d4 = (tid & 15) * 4;
        int bb = b0 + (row >> 3);
        float mt = MtM[(size_t)t * B_DIM + bb];
        #pragma unroll
        for (int i = 0; i < 4; ++i) {
            int d = d4 + i;
            float mean = obuf[d][row] + bp2[d];
            float lv   = obuf[d + 64][row] + bp2[64 + d];
            float xv = X[((size_t)t * B_DIM + bb) * DIN + d];
            float dm = xv - mean;
            float nll = 0.5f * (LOG_2PI_F + lv + dm * dm * __expf(-lv));
            racc = fmaf(mt, nll, racc);
        }
    }
    red2[tid] = racc;
    __syncthreads();
    for (int st = 256; st > 0; st >>= 1) {
        if (tid < st) red2[tid] += red2[tid + st];
        __syncthreads();
    }
    if (tid == 0) atomicAdd(loss_acc + 1, red2[0]);
}

// ---------------------------------------------------------------------------
// K4: finalize
// ---------------------------------------------------------------------------
__global__ void k4_final(const float* __restrict__ loss_acc, float* __restrict__ out)
{
    if (threadIdx.x == 0 && blockIdx.x == 0) {
        float kld   = loss_acc[0] * (0.5f * DT_F / (float)(B_DIM * S_DIM));
        float recon = loss_acc[1] * (1.0f / (float)(B_DIM * S_DIM));
        out[131072] = recon + kld;
        out[131073] = recon;
        out[131074] = kld;
    }
}

// ---------------------------------------------------------------------------
extern "C" void kernel_launch(void* const* d_in, const int* in_sizes, int n_in,
                              void* d_out, int out_size, void* d_ws, size_t ws_size,
                              hipStream_t stream)
{
    const float* X        = (const float*)d_in[0];
    const float* M        = (const float*)d_in[1];
    const float* cov      = (const float*)d_in[2];
    const float* path_h   = (const float*)d_in[3];
    const float* path_hpos= (const float*)d_in[4];
    const float* noise    = (const float*)d_in[5];
    const float* Wc1 = (const float*)d_in[6];
    const float* bc1 = (const float*)d_in[7];
    const float* Wc2 = (const float*)d_in[8];
    const float* bc2 = (const float*)d_in[9];
    const float* Wd1 = (const float*)d_in[10];
    const float* bd1 = (const float*)d_in[11];
    const float* Wd2 = (const float*)d_in[12];
    const float* bd2 = (const float*)d_in[13];
    const float* Wf1 = (const float*)d_in[14];
    const float* bf1 = (const float*)d_in[15];
    const float* Wf2 = (const float*)d_in[16];
    const float* bf2 = (const float*)d_in[17];
    const float* Wp1 = (const float*)d_in[18];
    const float* bp1 = (const float*)d_in[19];
    const float* Wp2 = (const float*)d_in[20];
    const float* bp2 = (const float*)d_in[21];
    float* out = (float*)d_out;

    // workspace layout (bytes, 256-aligned)
    char* ws = (char*)d_ws;
    size_t o = 0;
    float* z_state = (float*)(ws + o); o += 524288;          // [1024][128] f32
    float* loss    = (float*)(ws + o); o += 256;
    f16* WA   = (f16*)(ws + o); o += 131072;
    f16* WB   = (f16*)(ws + o); o += 131072;
    f16* WC   = (f16*)(ws + o); o += 131072;
    f16* WD   = (f16*)(ws + o); o += 131072;
    f16* W1A  = (f16*)(ws + o); o += 262144;
    f16* WF1  = (f16*)(ws + o); o += 262144;
    f16* WP1A = (f16*)(ws + o); o += 262144;
    f16* WF2  = (f16*)(ws + o); o += 131072;
    f16* HprF = (f16*)(ws + o); o += 16777216;               // [T*B][512] f16
    f16* HpoF = (f16*)(ws + o); o += 16777216;
    f16* HpF  = (f16*)(ws + o); o += 16777216;
    float* Diff = (float*)(ws + o); o += 8388608;            // [T*B][128] f32
    float* MtM  = (float*)(ws + o); o += 65536;              // [T*B] f32
    unsigned* ztraj = (unsigned*)(ws + o); o += 33554432;    // [T*1024][64] f16x2

    kw_frag<<<2816, 256, 0, stream>>>(Wd1, Wd2, Wp1, Wp2, Wf1, Wf2,
                                      WA, WB, WC, WD, W1A, WF1, WP1A, WF2);
    k0_init<<<B_DIM, 128, 0, stream>>>(cov, Wc1, bc1, Wc2, bc2, z_state, loss);
    k1_pre<<<256, 512, 0, stream>>>(path_h, path_hpos, M,
                                    W1A, WF1, WP1A, WF2,
                                    bd1, bf1, bf2, bp1,
                                    HprF, HpoF, HpF, Diff, MtM);
    k2_scan<<<256, 512, 0, stream>>>(WA, WB, HprF, HpoF, Diff, noise, bd2,
                                     z_state, ztraj, out, loss);
    k3_recon<<<4096, 512, 0, stream>>>(WC, WD, HpF, ztraj, X, MtM, bp2, loss);
    k4_final<<<1, 64, 0, stream>>>(loss, out);
}

// Round 5
// 591.278 us; speedup vs baseline: 14.8503x; 1.1486x over previous
//
#include <hip/hip_runtime.h>
#include <hip/hip_bf16.h>
#include <math.h>

// Problem dims (fixed by setup_inputs)
#define T_DIM 128
#define B_DIM 128
#define S_DIM 8
#define DIN   64
#define R_DIM 256
#define Z_DIM 128
#define H_DIM 512
#define C_DIM 32
#define CH_DIM 64

#define DT_F      0.05f
#define SQRT_DT_F 0.22360679774997896f
#define LOG_2PI_F 1.8378770664093453f

typedef _Float16 f16;
typedef __fp16 fp16x2 __attribute__((ext_vector_type(2)));
typedef _Float16 f16x8 __attribute__((ext_vector_type(8)));
typedef float f32x4 __attribute__((ext_vector_type(4)));
typedef unsigned u32x4 __attribute__((ext_vector_type(4)));

union U16x8 { uint4 u; f16x8 h; };

__device__ __forceinline__ f32x4 mfma16(const uint4& a, const uint4& b, f32x4 c) {
    U16x8 ua, ub; ua.u = a; ub.u = b;
    return __builtin_amdgcn_mfma_f32_16x16x32_f16(ua.h, ub.h, c, 0, 0, 0);
}

__device__ __forceinline__ f32x4 mfma16v(u32x4 a, u32x4 b, f32x4 c) {
    return __builtin_amdgcn_mfma_f32_16x16x32_f16(
        __builtin_bit_cast(f16x8, a), __builtin_bit_cast(f16x8, b), c, 0, 0, 0);
}

#define KEEPV(x) asm volatile("" : "+v"(x))

__device__ __forceinline__ unsigned pk2(float a, float b) {
    fp16x2 h = __builtin_amdgcn_cvt_pkrtz(a, b);
    return __builtin_bit_cast(unsigned, h);
}
__device__ __forceinline__ float upk_lo(unsigned u) {
    return (float)__builtin_bit_cast(f16, (unsigned short)(u & 0xffffu));
}
__device__ __forceinline__ float upk_hi(unsigned u) {
    return (float)__builtin_bit_cast(f16, (unsigned short)(u >> 16));
}

__device__ __forceinline__ float rcp_fast(float x) {
    return __builtin_amdgcn_rcpf(x);
}

__device__ __forceinline__ float tanh_fast(float x) {
    float ax = fabsf(x);
    float e  = __expf(-2.0f * ax);
    float r  = (1.0f - e) * rcp_fast(1.0f + e);
    return copysignf(r, x);
}

// ---------------------------------------------------------------------------
// KW: pre-fragment weights into MFMA A-frag layouts (f16).
// ---------------------------------------------------------------------------
__global__ __launch_bounds__(256) void kw_frag(
    const float* __restrict__ Wd1, const float* __restrict__ Wd2,
    const float* __restrict__ Wp1, const float* __restrict__ Wp2,
    const float* __restrict__ Wf1, const float* __restrict__ Wf2,
    f16* __restrict__ WA, f16* __restrict__ WB,
    f16* __restrict__ WC, f16* __restrict__ WD,
    f16* __restrict__ W1A, f16* __restrict__ WF1,
    f16* __restrict__ WP1A, f16* __restrict__ WF2)
{
    int gid = blockIdx.x * 256 + threadIdx.x;    // [0, 720896)
    const float* W; f16* dst; int k0, nktl, ld, off;
    if      (gid < 65536)  { W = Wd1; dst = WA;   k0 = 256; nktl = 2; ld = 512; off = gid; }
    else if (gid < 131072) { W = Wd2; dst = WB;   k0 = 0;   nktl = 4; ld = 128; off = gid - 65536; }
    else if (gid < 196608) { W = Wp1; dst = WC;   k0 = 256; nktl = 2; ld = 512; off = gid - 131072; }
    else if (gid < 262144) { W = Wp2; dst = WD;   k0 = 0;   nktl = 4; ld = 128; off = gid - 196608; }
    else if (gid < 393216) { W = Wd1; dst = W1A;  k0 = 0;   nktl = 3; ld = 512; off = gid - 262144; }
    else if (gid < 524288) { W = Wf1; dst = WF1;  k0 = 0;   nktl = 3; ld = 512; off = gid - 393216; }
    else if (gid < 655360) { W = Wp1; dst = WP1A; k0 = 0;   nktl = 3; ld = 512; off = gid - 524288; }
    else                   { W = Wf2; dst = WF2;  k0 = 0;   nktl = 4; ld = 128; off = gid - 655360; }
    int j = off & 7, l = (off >> 3) & 63, tile = off >> 9;
    int mt = tile >> nktl, kt = tile & ((1 << nktl) - 1);
    int lr = l & 15, lg = l >> 4;
    int c = mt * 16 + lr;
    int k = k0 + kt * 32 + 8 * lg + j;
    dst[off] = (f16)W[(size_t)k * ld + c];
}

// ---------------------------------------------------------------------------
// K0: z0 = tanh(mlp(cov)); zero loss accumulators.
// ---------------------------------------------------------------------------
__global__ __launch_bounds__(128) void k0_init(
    const float* __restrict__ cov,
    const float* __restrict__ Wc1, const float* __restrict__ bc1,
    const float* __restrict__ Wc2, const float* __restrict__ bc2,
    float* __restrict__ z_state, float* __restrict__ loss_acc)
{
    int b = blockIdx.x;
    int tid = threadIdx.x;
    __shared__ float covs[C_DIM];
    __shared__ float hid[CH_DIM];
    if (tid < C_DIM) covs[tid] = cov[b * C_DIM + tid];
    __syncthreads();
    if (tid < CH_DIM) {
        float a = bc1[tid];
        #pragma unroll
        for (int c = 0; c < C_DIM; ++c) a = fmaf(covs[c], Wc1[c * CH_DIM + tid], a);
        hid[tid] = fmaxf(a, 0.0f);
    }
    __syncthreads();
    float a = bc2[tid];
    #pragma unroll 8
    for (int h = 0; h < CH_DIM; ++h) a = fmaf(hid[h], Wc2[h * Z_DIM + tid], a);
    float z0 = tanh_fast(a);
    #pragma unroll
    for (int s = 0; s < S_DIM; ++s)
        z_state[((size_t)b * S_DIM + s) * Z_DIM + tid] = z0;
    if (b == 0 && tid < 2) loss_acc[tid] = 0.0f;
}

// ---------------------------------------------------------------------------
// K1 (MFMA): per block 64 rows, 8 waves. Same as R4 (passed).
// ---------------------------------------------------------------------------
__global__ __launch_bounds__(512, 1) void k1_pre(
    const float* __restrict__ path_h, const float* __restrict__ path_hpos,
    const float* __restrict__ M,
    const f16* __restrict__ W1A, const f16* __restrict__ WF1,
    const f16* __restrict__ WP1A, const f16* __restrict__ WF2,
    const float* __restrict__ bd1, const float* __restrict__ bf1,
    const float* __restrict__ bf2, const float* __restrict__ bp1,
    f16* __restrict__ HprF, f16* __restrict__ HpoF, f16* __restrict__ HpF,
    float* __restrict__ Diff, float* __restrict__ MtM)
{
    const int base = blockIdx.x * 64;
    const int tid = threadIdx.x;
    const int wv = tid >> 6, l = tid & 63;
    const int lr = l & 15, lg = l >> 4;

    __shared__ uint4 ABf[2][4][8][64];
    __shared__ uint4 FHf[4][16][64];

    {
        int row = base + (tid >> 3), sg = tid & 7;
        const float4* mp = (const float4*)(M + (size_t)row * DIN + sg * 8);
        float4 m0 = mp[0], m1 = mp[1];
        float sm = m0.x + m0.y + m0.z + m0.w + m1.x + m1.y + m1.z + m1.w;
        sm += __shfl_xor(sm, 1);
        sm += __shfl_xor(sm, 2);
        sm += __shfl_xor(sm, 4);
        if (sg == 0) MtM[row] = sm * (1.0f / 64.0f);
    }

    for (int it = 0; it < 4; ++it) {
        int s = it * 512 + tid;
        int ktkg = s & 31, n = (s >> 5) & 15, nt = s >> 9;
        int kt = ktkg >> 2, kg = ktkg & 3;
        int row = base + nt * 16 + n;
        const float4* ph4 = (const float4*)(path_h    + (size_t)row * R_DIM + kt * 32 + kg * 8);
        const float4* pp4 = (const float4*)(path_hpos + (size_t)row * R_DIM + kt * 32 + kg * 8);
        float4 a0 = ph4[0], a1 = ph4[1];
        float4 p0 = pp4[0], p1 = pp4[1];
        uint4 ua, us;
        ua.x = pk2(a0.x, a0.y); ua.y = pk2(a0.z, a0.w);
        ua.z = pk2(a1.x, a1.y); ua.w = pk2(a1.z, a1.w);
        us.x = pk2(a0.x + p0.x, a0.y + p0.y); us.y = pk2(a0.z + p0.z, a0.w + p0.w);
        us.z = pk2(a1.x + p1.x, a1.y + p1.y); us.w = pk2(a1.z + p1.z, a1.w + p1.w);
        int ll = n + 16 * kg;
        ABf[0][nt][kt][ll] = ua;
        ABf[1][nt][kt][ll] = us;
    }
    __syncthreads();

    // ---- GEMM1: Hpr & Hpo
    {
        f32x4 accP[4][4], accQ[4][4];
        #pragma unroll
        for (int mt = 0; mt < 4; ++mt)
            #pragma unroll
            for (int nt = 0; nt < 4; ++nt) { accP[mt][nt] = (f32x4)0.f; accQ[mt][nt] = (f32x4)0.f; }
        for (int kt = 0; kt < 8; ++kt) {
            uint4 wa[4], bA[4], bS[4];
            #pragma unroll
            for (int mt = 0; mt < 4; ++mt)
                wa[mt] = ((const uint4*)W1A)[(size_t)((wv * 4 + mt) * 8 + kt) * 64 + l];
            #pragma unroll
            for (int nt = 0; nt < 4; ++nt) { bA[nt] = ABf[0][nt][kt][l]; bS[nt] = ABf[1][nt][kt][l]; }
            #pragma unroll
            for (int mt = 0; mt < 4; ++mt)
                #pragma unroll
                for (int nt = 0; nt < 4; ++nt) {
                    accP[mt][nt] = mfma16(wa[mt], bA[nt], accP[mt][nt]);
                    accQ[mt][nt] = mfma16(wa[mt], bS[nt], accQ[mt][nt]);
                }
        }
        #pragma unroll
        for (int mt = 0; mt < 4; ++mt) {
            int c0 = wv * 64 + mt * 16 + 4 * lg;
            float4 bv = *(const float4*)&bd1[c0];
            #pragma unroll
            for (int nt = 0; nt < 4; ++nt) {
                size_t o = (size_t)(base + nt * 16 + lr) * H_DIM + c0;
                uint2 wp, wq;
                wp.x = pk2(accP[mt][nt][0] + bv.x, accP[mt][nt][1] + bv.y);
                wp.y = pk2(accP[mt][nt][2] + bv.z, accP[mt][nt][3] + bv.w);
                wq.x = pk2(accQ[mt][nt][0] + bv.x, accQ[mt][nt][1] + bv.y);
                wq.y = pk2(accQ[mt][nt][2] + bv.z, accQ[mt][nt][3] + bv.w);
                *(uint2*)&HprF[o] = wp;
                *(uint2*)&HpoF[o] = wq;
            }
        }
    }

    // ---- GEMM2: Hp
    {
        f32x4 accH[4][4];
        #pragma unroll
        for (int mt = 0; mt < 4; ++mt)
            #pragma unroll
            for (int nt = 0; nt < 4; ++nt) accH[mt][nt] = (f32x4)0.f;
        for (int kt = 0; kt < 8; ++kt) {
            uint4 wa[4], bA[4];
            #pragma unroll
            for (int mt = 0; mt < 4; ++mt)
                wa[mt] = ((const uint4*)WP1A)[(size_t)((wv * 4 + mt) * 8 + kt) * 64 + l];
            #pragma unroll
            for (int nt = 0; nt < 4; ++nt) bA[nt] = ABf[0][nt][kt][l];
            #pragma unroll
            for (int mt = 0; mt < 4; ++mt)
                #pragma unroll
                for (int nt = 0; nt < 4; ++nt) accH[mt][nt] = mfma16(wa[mt], bA[nt], accH[mt][nt]);
        }
        #pragma unroll
        for (int mt = 0; mt < 4; ++mt) {
            int c0 = wv * 64 + mt * 16 + 4 * lg;
            float4 bv = *(const float4*)&bp1[c0];
            #pragma unroll
            for (int nt = 0; nt < 4; ++nt) {
                size_t o = (size_t)(base + nt * 16 + lr) * H_DIM + c0;
                uint2 wp;
                wp.x = pk2(accH[mt][nt][0] + bv.x, accH[mt][nt][1] + bv.y);
                wp.y = pk2(accH[mt][nt][2] + bv.z, accH[mt][nt][3] + bv.w);
                *(uint2*)&HpF[o] = wp;
            }
        }
    }

    // ---- GEMM3: fh
    {
        f32x4 accF[4][4];
        #pragma unroll
        for (int mt = 0; mt < 4; ++mt)
            #pragma unroll
            for (int nt = 0; nt < 4; ++nt) accF[mt][nt] = (f32x4)0.f;
        for (int kt = 0; kt < 8; ++kt) {
            uint4 wa[4], bA[4];
            #pragma unroll
            for (int mt = 0; mt < 4; ++mt)
                wa[mt] = ((const uint4*)WF1)[(size_t)((wv * 4 + mt) * 8 + kt) * 64 + l];
            #pragma unroll
            for (int nt = 0; nt < 4; ++nt) bA[nt] = ABf[0][nt][kt][l];
            #pragma unroll
            for (int mt = 0; mt < 4; ++mt)
                #pragma unroll
                for (int nt = 0; nt < 4; ++nt) accF[mt][nt] = mfma16(wa[mt], bA[nt], accF[mt][nt]);
        }
        #pragma unroll
        for (int mt = 0; mt < 4; ++mt) {
            int c0 = wv * 64 + mt * 16 + 4 * lg;
            float4 bv = *(const float4*)&bf1[c0];
            int kt2 = c0 >> 5;
            int l2  = lr + 16 * ((c0 >> 3) & 3);
            int half = (c0 & 7) >> 2;
            #pragma unroll
            for (int nt = 0; nt < 4; ++nt) {
                uint2 wp;
                wp.x = pk2(fmaxf(accF[mt][nt][0] + bv.x, 0.f), fmaxf(accF[mt][nt][1] + bv.y, 0.f));
                wp.y = pk2(fmaxf(accF[mt][nt][2] + bv.z, 0.f), fmaxf(accF[mt][nt][3] + bv.w, 0.f));
                ((uint2*)&FHf[nt][kt2][l2])[half] = wp;
            }
        }
    }
    __syncthreads();

    // ---- GEMM4: Diff
    {
        f32x4 accD[4];
        #pragma unroll
        for (int nt = 0; nt < 4; ++nt) accD[nt] = (f32x4)0.f;
        for (int kt = 0; kt < 16; ++kt) {
            uint4 wf = ((const uint4*)WF2)[(size_t)(wv * 16 + kt) * 64 + l];
            #pragma unroll
            for (int nt = 0; nt < 4; ++nt) accD[nt] = mfma16(wf, FHf[nt][kt][l], accD[nt]);
        }
        int c0 = wv * 16 + 4 * lg;
        float4 bv = *(const float4*)&bf2[c0];
        #pragma unroll
        for (int nt = 0; nt < 4; ++nt) {
            float4 o;
            o.x = __expf(accD[nt][0] + bv.x);
            o.y = __expf(accD[nt][1] + bv.y);
            o.z = __expf(accD[nt][2] + bv.z);
            o.w = __expf(accD[nt][3] + bv.w);
            *(float4*)&Diff[(size_t)(base + nt * 16 + lr) * Z_DIM + c0] = o;
        }
    }
}

// ---------------------------------------------------------------------------
// K2: MFMA scan. 256 blocks x 512 threads (8 waves).
// Weights pinned in VGPRs via asm; broadcast-safe LDS frag reads; rcp math;
// global streams software-pipelined one iteration ahead.
// ---------------------------------------------------------------------------
__global__ __launch_bounds__(512, 1) void k2_scan(
    const f16* __restrict__ WA, const f16* __restrict__ WB,
    const f16* __restrict__ HprF, const f16* __restrict__ HpoF,
    const float* __restrict__ Diff, const float* __restrict__ noise,
    const float* __restrict__ bd2,
    const float* __restrict__ z_state, unsigned* __restrict__ ztraj_u,
    float* __restrict__ out_z, float* __restrict__ loss_acc)
{
    const int b  = blockIdx.x >> 1;
    const int sh = blockIdx.x & 1;
    const int tid = threadIdx.x;
    const int wv = tid >> 6, l = tid & 63;
    const int lr = l & 15, lg = l >> 4;
    const bool owner = (lr < 4);
    const int lsafe = (l & 48) | (lr & 3);   // broadcast-read slot (defined data)

    __shared__ u32x4 zfrag[4][64];          // 4 KB
    __shared__ u32x4 phfrag[16][64];        // 16 KB
    __shared__ u32x4 qhfrag[16][64];        // 16 KB
    __shared__ float red2[512];

    // ---- weights -> VGPR, pinned
    u32x4 wa[4][4];
    #pragma unroll
    for (int mt = 0; mt < 4; ++mt)
        #pragma unroll
        for (int kt = 0; kt < 4; ++kt)
            wa[mt][kt] = ((const u32x4*)WA)[(size_t)((wv * 4 + mt) * 4 + kt) * 64 + l];
    u32x4 wb[16];
    #pragma unroll
    for (int kt = 0; kt < 16; ++kt)
        wb[kt] = ((const u32x4*)WB)[(size_t)(wv * 16 + kt) * 64 + l];
    #pragma unroll
    for (int mt = 0; mt < 4; ++mt)
        #pragma unroll
        for (int kt = 0; kt < 4; ++kt) KEEPV(wa[mt][kt]);
    #pragma unroll
    for (int kt = 0; kt < 16; ++kt) KEEPV(wb[kt]);

    // ---- owner state
    const int j0 = wv * 16 + 4 * lg;        // z columns [j0, j0+4)
    const int srow = sh * 4 + lr;           // s index (owners)
    float zreg[4] = {0.f, 0.f, 0.f, 0.f};
    float bdv[4] = {0.f, 0.f, 0.f, 0.f};
    uint2* zslot = ((uint2*)&zfrag[wv >> 1][lr + 16 * (2 * (wv & 1) + (lg >> 1))]) + (lg & 1);
    if (owner) {
        *(float4*)zreg = *(const float4*)&z_state[((size_t)b * S_DIM + srow) * Z_DIM + j0];
        *(float4*)bdv  = *(const float4*)&bd2[j0];
        uint2 zz; zz.x = pk2(zreg[0], zreg[1]); zz.y = pk2(zreg[2], zreg[3]);
        *zslot = zz;
    }

    // ---- prefetch t=0 streams (owner lanes)
    uint2 hp[4], hq[4];
    float4 dif, ep;
    if (owner) {
        #pragma unroll
        for (int mt = 0; mt < 4; ++mt) {
            int c0 = wv * 64 + mt * 16 + 4 * lg;
            hp[mt] = *(const uint2*)&HprF[(size_t)b * H_DIM + c0];
            hq[mt] = *(const uint2*)&HpoF[(size_t)b * H_DIM + c0];
        }
        dif = *(const float4*)&Diff[(size_t)b * Z_DIM + j0];
        ep  = *(const float4*)&noise[((size_t)b * S_DIM + srow) * Z_DIM + j0];
    }
    __syncthreads();

    float kacc = 0.f;

    for (int t = 0; t < T_DIM; ++t) {
        // -------- phase A: G^T = Wd1z^T @ z^T, epilogue -> ph/qh frags
        u32x4 zb[4];
        #pragma unroll
        for (int kt = 0; kt < 4; ++kt) zb[kt] = zfrag[kt][lsafe];
        #pragma unroll
        for (int mt = 0; mt < 4; ++mt) {
            f32x4 acc = (f32x4)0.f;
            #pragma unroll
            for (int kt = 0; kt < 4; ++kt) acc = mfma16v(wa[mt][kt], zb[kt], acc);
            if (owner) {
                fp16x2 zero2 = {(__fp16)0.f, (__fp16)0.f};
                fp16x2 a01 = __builtin_amdgcn_cvt_pkrtz(acc[0], acc[1]);
                fp16x2 a23 = __builtin_amdgcn_cvt_pkrtz(acc[2], acc[3]);
                fp16x2 p01 = __builtin_elementwise_max(a01 + __builtin_bit_cast(fp16x2, hp[mt].x), zero2);
                fp16x2 p23 = __builtin_elementwise_max(a23 + __builtin_bit_cast(fp16x2, hp[mt].y), zero2);
                fp16x2 q01 = __builtin_elementwise_max(a01 + __builtin_bit_cast(fp16x2, hq[mt].x), zero2);
                fp16x2 q23 = __builtin_elementwise_max(a23 + __builtin_bit_cast(fp16x2, hq[mt].y), zero2);
                int c0 = wv * 64 + mt * 16 + 4 * lg;
                int ktp = c0 >> 5;
                int l2  = lr + 16 * ((c0 >> 3) & 3);
                int half = (c0 & 7) >> 2;
                uint2 wp, wq;
                wp.x = __builtin_bit_cast(unsigned, p01); wp.y = __builtin_bit_cast(unsigned, p23);
                wq.x = __builtin_bit_cast(unsigned, q01); wq.y = __builtin_bit_cast(unsigned, q23);
                ((uint2*)&phfrag[ktp][l2])[half] = wp;
                ((uint2*)&qhfrag[ktp][l2])[half] = wq;
            }
        }

        // -------- prefetch t+1 streams (in flight across barrier + phase B)
        int tn = (t + 1 < T_DIM) ? (t + 1) : t;
        uint2 hpn[4], hqn[4];
        float4 difn, epn;
        if (owner) {
            size_t hbn = ((size_t)tn * B_DIM + b) * H_DIM;
            #pragma unroll
            for (int mt = 0; mt < 4; ++mt) {
                int c0 = wv * 64 + mt * 16 + 4 * lg;
                hpn[mt] = *(const uint2*)&HprF[hbn + c0];
                hqn[mt] = *(const uint2*)&HpoF[hbn + c0];
            }
            difn = *(const float4*)&Diff[((size_t)tn * B_DIM + b) * Z_DIM + j0];
            epn  = *(const float4*)&noise[(((size_t)tn * B_DIM + b) * S_DIM + srow) * Z_DIM + j0];
        }
        __syncthreads();

        // -------- phase B: P/Q^T = Wd2^T @ {ph,qh}^T; z update; kld
        f32x4 aP = (f32x4)0.f, aQ = (f32x4)0.f;
        #pragma unroll
        for (int kt = 0; kt < 16; ++kt) {
            u32x4 pb = phfrag[kt][lsafe];
            u32x4 qb = qhfrag[kt][lsafe];
            aP = mfma16v(wb[kt], pb, aP);
            aQ = mfma16v(wb[kt], qb, aQ);
        }
        if (owner) {
            const float* difp = (const float*)&dif;
            const float* epp  = (const float*)&ep;
            #pragma unroll
            for (int i = 0; i < 4; ++i) {
                float pr = 0.1f * tanh_fast(aP[i] + bdv[i]);
                float po = 0.1f * tanh_fast(aQ[i] + bdv[i]);
                float dv = difp[i];
                zreg[i] = zreg[i] + DT_F * po + SQRT_DT_F * dv * epp[i];
                float e = (pr - po) * rcp_fast(dv);
                kacc = fmaf(e, e, kacc);
            }
            uint2 zz; zz.x = pk2(zreg[0], zreg[1]); zz.y = pk2(zreg[2], zreg[3]);
            *zslot = zz;
            *(uint2*)&ztraj_u[((size_t)t * 1024 + (size_t)b * S_DIM + srow) * 64 + (j0 >> 1)] = zz;
        }
        // rotate prefetch
        #pragma unroll
        for (int mt = 0; mt < 4; ++mt) { hp[mt] = hpn[mt]; hq[mt] = hqn[mt]; }
        dif = difn; ep = epn;
        __syncthreads();
    }

    // ---- final z out
    if (owner)
        *(float4*)&out_z[((size_t)b * S_DIM + srow) * Z_DIM + j0] = *(const float4*)zreg;

    // ---- kld reduce
    red2[tid] = kacc;
    __syncthreads();
    for (int st = 256; st > 0; st >>= 1) {
        if (tid < st) red2[tid] += red2[tid + st];
        __syncthreads();
    }
    if (tid == 0) atomicAdd(loss_acc + 0, red2[0]);
}

// ---------------------------------------------------------------------------
// K3: recon (phases C/D), fully parallel over (t,b,s). 4096 blocks x 512 thr.
// ---------------------------------------------------------------------------
__global__ __launch_bounds__(512, 2) void k3_recon(
    const f16* __restrict__ WC, const f16* __restrict__ WD,
    const f16* __restrict__ HpF, const unsigned* __restrict__ ztraj_u,
    const float* __restrict__ X, const float* __restrict__ MtM,
    const float* __restrict__ bp2, float* __restrict__ loss_acc)
{
    const int t  = blockIdx.x >> 5;
    const int b0 = (blockIdx.x & 31) * 4;
    const int tid = threadIdx.x;
    const int wv = tid >> 6, l = tid & 63;
    const int lr = l & 15, lg = l >> 4;

    __shared__ uint4 zfrag[4][2][64];
    __shared__ uint4 pwfrag[16][2][64];
    __shared__ float obuf[128][33];
    __shared__ float red2[512];

    uint4 wc[4][4];
    #pragma unroll
    for (int mt = 0; mt < 4; ++mt)
        #pragma unroll
        for (int kt = 0; kt < 4; ++kt)
            wc[mt][kt] = ((const uint4*)WC)[(size_t)((wv * 4 + mt) * 4 + kt) * 64 + l];
    uint4 wd[16];
    #pragma unroll
    for (int kt = 0; kt < 16; ++kt)
        wd[kt] = ((const uint4*)WD)[(size_t)(wv * 16 + kt) * 64 + l];

    {
        int kt = tid >> 7;
        int nt = (tid >> 6) & 1;
        int ll = tid & 63;
        int n = ll & 15, kg = ll >> 4;
        int rl = nt * 16 + n;
        size_t grow = (size_t)t * 1024 + (size_t)b0 * S_DIM + rl;
        zfrag[kt][nt][ll] = *(const uint4*)&ztraj_u[grow * 64 + kt * 16 + kg * 4];
    }
    __syncthreads();

    f16* pwf = (f16*)pwfrag;
    #pragma unroll
    for (int nt = 0; nt < 2; ++nt) {
        #pragma unroll
        for (int mt = 0; mt < 4; ++mt) {
            f32x4 acc = (f32x4)0.f;
            #pragma unroll
            for (int kt = 0; kt < 4; ++kt) acc = mfma16(wc[mt][kt], zfrag[kt][nt][l], acc);
            int c0 = wv * 64 + mt * 16 + 4 * lg;
            int rl = nt * 16 + lr;
            int bb = b0 + (rl >> 3);
            size_t hbs = ((size_t)t * B_DIM + bb) * H_DIM;
            uint2 hpv = *(const uint2*)&HpF[hbs + c0];
            float p0 = fmaxf(acc[0] + upk_lo(hpv.x), 0.f);
            float p1 = fmaxf(acc[1] + upk_hi(hpv.x), 0.f);
            float p2 = fmaxf(acc[2] + upk_lo(hpv.y), 0.f);
            float p3 = fmaxf(acc[3] + upk_hi(hpv.y), 0.f);
            int ktp = c0 >> 5;
            int lp  = lr + 16 * ((c0 >> 3) & 3);
            int off = c0 & 7;
            uint2 wp; wp.x = pk2(p0, p1); wp.y = pk2(p2, p3);
            *(uint2*)&pwf[(size_t)((ktp * 2 + nt) * 64 + lp) * 8 + off] = wp;
        }
    }
    __syncthreads();

    #pragma unroll
    for (int nt = 0; nt < 2; ++nt) {
        f32x4 acc = (f32x4)0.f;
        #pragma unroll
        for (int kt = 0; kt < 16; ++kt) acc = mfma16(wd[kt], pwfrag[kt][nt][l], acc);
        int m0 = wv * 16 + 4 * lg;
        int row = nt * 16 + lr;
        #pragma unroll
        for (int i = 0; i < 4; ++i) obuf[m0 + i][row] = acc[i];
    }
    __syncthreads();

    float racc = 0.f;
    {
        int row = tid >> 4;
        int d4 = (tid & 15) * 4;
        int bb = b0 + (row >> 3);
        float mt = MtM[(size_t)t * B_DIM + bb];
        #pragma unroll
        for (int i = 0; i < 4; ++i) {
            int d = d4 + i;
            float mean = obuf[d][row] + bp2[d];
            float lv   = obuf[d + 64][row] + bp2[64 + d];
            float xv = X[((size_t)t * B_DIM + bb) * DIN + d];
            float dm = xv - mean;
            float nll = 0.5f * (LOG_2PI_F + lv + dm * dm * __expf(-lv));
            racc = fmaf(mt, nll, racc);
        }
    }
    red2[tid] = racc;
    __syncthreads();
    for (int st = 256; st > 0; st >>= 1) {
        if (tid < st) red2[tid] += red2[tid + st];
        __syncthreads();
    }
    if (tid == 0) atomicAdd(loss_acc + 1, red2[0]);
}

// ---------------------------------------------------------------------------
// K4: finalize
// ---------------------------------------------------------------------------
__global__ void k4_final(const float* __restrict__ loss_acc, float* __restrict__ out)
{
    if (threadIdx.x == 0 && blockIdx.x == 0) {
        float kld   = loss_acc[0] * (0.5f * DT_F / (float)(B_DIM * S_DIM));
        float recon = loss_acc[1] * (1.0f / (float)(B_DIM * S_DIM));
        out[131072] = recon + kld;
        out[131073] = recon;
        out[131074] = kld;
    }
}

// ---------------------------------------------------------------------------
extern "C" void kernel_launch(void* const* d_in, const int* in_sizes, int n_in,
                              void* d_out, int out_size, void* d_ws, size_t ws_size,
                              hipStream_t stream)
{
    const float* X        = (const float*)d_in[0];
    const float* M        = (const float*)d_in[1];
    const float* cov      = (const float*)d_in[2];
    const float* path_h   = (const float*)d_in[3];
    const float* path_hpos= (const float*)d_in[4];
    const float* noise    = (const float*)d_in[5];
    const float* Wc1 = (const float*)d_in[6];
    const float* bc1 = (const float*)d_in[7];
    const float* Wc2 = (const float*)d_in[8];
    const float* bc2 = (const float*)d_in[9];
    const float* Wd1 = (const float*)d_in[10];
    const float* bd1 = (const float*)d_in[11];
    const float* Wd2 = (const float*)d_in[12];
    const float* bd2 = (const float*)d_in[13];
    const float* Wf1 = (const float*)d_in[14];
    const float* bf1 = (const float*)d_in[15];
    const float* Wf2 = (const float*)d_in[16];
    const float* bf2 = (const float*)d_in[17];
    const float* Wp1 = (const float*)d_in[18];
    const float* bp1 = (const float*)d_in[19];
    const float* Wp2 = (const float*)d_in[20];
    const float* bp2 = (const float*)d_in[21];
    float* out = (float*)d_out;

    // workspace layout (bytes, 256-aligned)
    char* ws = (char*)d_ws;
    size_t o = 0;
    float* z_state = (float*)(ws + o); o += 524288;
    float* loss    = (float*)(ws + o); o += 256;
    f16* WA   = (f16*)(ws + o); o += 131072;
    f16* WB   = (f16*)(ws + o); o += 131072;
    f16* WC   = (f16*)(ws + o); o += 131072;
    f16* WD   = (f16*)(ws + o); o += 131072;
    f16* W1A  = (f16*)(ws + o); o += 262144;
    f16* WF1  = (f16*)(ws + o); o += 262144;
    f16* WP1A = (f16*)(ws + o); o += 262144;
    f16* WF2  = (f16*)(ws + o); o += 131072;
    f16* HprF = (f16*)(ws + o); o += 16777216;
    f16* HpoF = (f16*)(ws + o); o += 16777216;
    f16* HpF  = (f16*)(ws + o); o += 16777216;
    float* Diff = (float*)(ws + o); o += 8388608;
    float* MtM  = (float*)(ws + o); o += 65536;
    unsigned* ztraj = (unsigned*)(ws + o); o += 33554432;

    kw_frag<<<2816, 256, 0, stream>>>(Wd1, Wd2, Wp1, Wp2, Wf1, Wf2,
                                      WA, WB, WC, WD, W1A, WF1, WP1A, WF2);
    k0_init<<<B_DIM, 128, 0, stream>>>(cov, Wc1, bc1, Wc2, bc2, z_state, loss);
    k1_pre<<<256, 512, 0, stream>>>(path_h, path_hpos, M,
                                    W1A, WF1, WP1A, WF2,
                                    bd1, bf1, bf2, bp1,
                                    HprF, HpoF, HpF, Diff, MtM);
    k2_scan<<<256, 512, 0, stream>>>(WA, WB, HprF, HpoF, Diff, noise, bd2,
                                     z_state, ztraj, out, loss);
    k3_recon<<<4096, 512, 0, stream>>>(WC, WD, HpF, ztraj, X, MtM, bp2, loss);
    k4_final<<<1, 64, 0, stream>>>(loss, out);
}

// Round 6
// 555.666 us; speedup vs baseline: 15.8021x; 1.0641x over previous
//
#include <hip/hip_runtime.h>
#include <hip/hip_bf16.h>
#include <math.h>

// Problem dims (fixed by setup_inputs)
#define T_DIM 128
#define B_DIM 128
#define S_DIM 8
#define DIN   64
#define R_DIM 256
#define Z_DIM 128
#define H_DIM 512
#define C_DIM 32
#define CH_DIM 64

#define DT_F      0.05f
#define SQRT_DT_F 0.22360679774997896f
#define LOG_2PI_F 1.8378770664093453f

typedef _Float16 f16;
typedef __fp16 fp16x2 __attribute__((ext_vector_type(2)));
typedef _Float16 f16x8 __attribute__((ext_vector_type(8)));
typedef float f32x4 __attribute__((ext_vector_type(4)));
typedef unsigned u32x4 __attribute__((ext_vector_type(4)));

union U16x8 { uint4 u; f16x8 h; };

__device__ __forceinline__ f32x4 mfma16(const uint4& a, const uint4& b, f32x4 c) {
    U16x8 ua, ub; ua.u = a; ub.u = b;
    return __builtin_amdgcn_mfma_f32_16x16x32_f16(ua.h, ub.h, c, 0, 0, 0);
}

__device__ __forceinline__ f32x4 mfma16v(u32x4 a, u32x4 b, f32x4 c) {
    return __builtin_amdgcn_mfma_f32_16x16x32_f16(
        __builtin_bit_cast(f16x8, a), __builtin_bit_cast(f16x8, b), c, 0, 0, 0);
}

// Pin a 128-bit value into the AGPR file (gfx950 unified RF; MFMA reads AGPR
// operands directly). Remat of an AGPR needs load+v_accvgpr_write, which the
// allocator won't synthesize -> value stays resident.
#define KEEPA(x) asm volatile("" : "+a"(x))

__device__ __forceinline__ unsigned pk2(float a, float b) {
    fp16x2 h = __builtin_amdgcn_cvt_pkrtz(a, b);
    return __builtin_bit_cast(unsigned, h);
}
__device__ __forceinline__ float upk_lo(unsigned u) {
    return (float)__builtin_bit_cast(f16, (unsigned short)(u & 0xffffu));
}
__device__ __forceinline__ float upk_hi(unsigned u) {
    return (float)__builtin_bit_cast(f16, (unsigned short)(u >> 16));
}

__device__ __forceinline__ float rcp_fast(float x) {
    return __builtin_amdgcn_rcpf(x);
}

__device__ __forceinline__ float tanh_fast(float x) {
    float ax = fabsf(x);
    float e  = __expf(-2.0f * ax);
    float r  = (1.0f - e) * rcp_fast(1.0f + e);
    return copysignf(r, x);
}

// ---------------------------------------------------------------------------
// KW: pre-fragment weights into MFMA A-frag layouts (f16).
// ---------------------------------------------------------------------------
__global__ __launch_bounds__(256) void kw_frag(
    const float* __restrict__ Wd1, const float* __restrict__ Wd2,
    const float* __restrict__ Wp1, const float* __restrict__ Wp2,
    const float* __restrict__ Wf1, const float* __restrict__ Wf2,
    f16* __restrict__ WA, f16* __restrict__ WB,
    f16* __restrict__ WC, f16* __restrict__ WD,
    f16* __restrict__ W1A, f16* __restrict__ WF1,
    f16* __restrict__ WP1A, f16* __restrict__ WF2)
{
    int gid = blockIdx.x * 256 + threadIdx.x;    // [0, 720896)
    const float* W; f16* dst; int k0, nktl, ld, off;
    if      (gid < 65536)  { W = Wd1; dst = WA;   k0 = 256; nktl = 2; ld = 512; off = gid; }
    else if (gid < 131072) { W = Wd2; dst = WB;   k0 = 0;   nktl = 4; ld = 128; off = gid - 65536; }
    else if (gid < 196608) { W = Wp1; dst = WC;   k0 = 256; nktl = 2; ld = 512; off = gid - 131072; }
    else if (gid < 262144) { W = Wp2; dst = WD;   k0 = 0;   nktl = 4; ld = 128; off = gid - 196608; }
    else if (gid < 393216) { W = Wd1; dst = W1A;  k0 = 0;   nktl = 3; ld = 512; off = gid - 262144; }
    else if (gid < 524288) { W = Wf1; dst = WF1;  k0 = 0;   nktl = 3; ld = 512; off = gid - 393216; }
    else if (gid < 655360) { W = Wp1; dst = WP1A; k0 = 0;   nktl = 3; ld = 512; off = gid - 524288; }
    else                   { W = Wf2; dst = WF2;  k0 = 0;   nktl = 4; ld = 128; off = gid - 655360; }
    int j = off & 7, l = (off >> 3) & 63, tile = off >> 9;
    int mt = tile >> nktl, kt = tile & ((1 << nktl) - 1);
    int lr = l & 15, lg = l >> 4;
    int c = mt * 16 + lr;
    int k = k0 + kt * 32 + 8 * lg + j;
    dst[off] = (f16)W[(size_t)k * ld + c];
}

// ---------------------------------------------------------------------------
// K0: z0 = tanh(mlp(cov)); zero loss accumulators.
// ---------------------------------------------------------------------------
__global__ __launch_bounds__(128) void k0_init(
    const float* __restrict__ cov,
    const float* __restrict__ Wc1, const float* __restrict__ bc1,
    const float* __restrict__ Wc2, const float* __restrict__ bc2,
    float* __restrict__ z_state, float* __restrict__ loss_acc)
{
    int b = blockIdx.x;
    int tid = threadIdx.x;
    __shared__ float covs[C_DIM];
    __shared__ float hid[CH_DIM];
    if (tid < C_DIM) covs[tid] = cov[b * C_DIM + tid];
    __syncthreads();
    if (tid < CH_DIM) {
        float a = bc1[tid];
        #pragma unroll
        for (int c = 0; c < C_DIM; ++c) a = fmaf(covs[c], Wc1[c * CH_DIM + tid], a);
        hid[tid] = fmaxf(a, 0.0f);
    }
    __syncthreads();
    float a = bc2[tid];
    #pragma unroll 8
    for (int h = 0; h < CH_DIM; ++h) a = fmaf(hid[h], Wc2[h * Z_DIM + tid], a);
    float z0 = tanh_fast(a);
    #pragma unroll
    for (int s = 0; s < S_DIM; ++s)
        z_state[((size_t)b * S_DIM + s) * Z_DIM + tid] = z0;
    if (b == 0 && tid < 2) loss_acc[tid] = 0.0f;
}

// ---------------------------------------------------------------------------
// K1 (MFMA): per block 64 rows, 8 waves. Unchanged from R4/R5 (passed).
// ---------------------------------------------------------------------------
__global__ __launch_bounds__(512, 1) void k1_pre(
    const float* __restrict__ path_h, const float* __restrict__ path_hpos,
    const float* __restrict__ M,
    const f16* __restrict__ W1A, const f16* __restrict__ WF1,
    const f16* __restrict__ WP1A, const f16* __restrict__ WF2,
    const float* __restrict__ bd1, const float* __restrict__ bf1,
    const float* __restrict__ bf2, const float* __restrict__ bp1,
    f16* __restrict__ HprF, f16* __restrict__ HpoF, f16* __restrict__ HpF,
    float* __restrict__ Diff, float* __restrict__ MtM)
{
    const int base = blockIdx.x * 64;
    const int tid = threadIdx.x;
    const int wv = tid >> 6, l = tid & 63;
    const int lr = l & 15, lg = l >> 4;

    __shared__ uint4 ABf[2][4][8][64];
    __shared__ uint4 FHf[4][16][64];

    {
        int row = base + (tid >> 3), sg = tid & 7;
        const float4* mp = (const float4*)(M + (size_t)row * DIN + sg * 8);
        float4 m0 = mp[0], m1 = mp[1];
        float sm = m0.x + m0.y + m0.z + m0.w + m1.x + m1.y + m1.z + m1.w;
        sm += __shfl_xor(sm, 1);
        sm += __shfl_xor(sm, 2);
        sm += __shfl_xor(sm, 4);
        if (sg == 0) MtM[row] = sm * (1.0f / 64.0f);
    }

    for (int it = 0; it < 4; ++it) {
        int s = it * 512 + tid;
        int ktkg = s & 31, n = (s >> 5) & 15, nt = s >> 9;
        int kt = ktkg >> 2, kg = ktkg & 3;
        int row = base + nt * 16 + n;
        const float4* ph4 = (const float4*)(path_h    + (size_t)row * R_DIM + kt * 32 + kg * 8);
        const float4* pp4 = (const float4*)(path_hpos + (size_t)row * R_DIM + kt * 32 + kg * 8);
        float4 a0 = ph4[0], a1 = ph4[1];
        float4 p0 = pp4[0], p1 = pp4[1];
        uint4 ua, us;
        ua.x = pk2(a0.x, a0.y); ua.y = pk2(a0.z, a0.w);
        ua.z = pk2(a1.x, a1.y); ua.w = pk2(a1.z, a1.w);
        us.x = pk2(a0.x + p0.x, a0.y + p0.y); us.y = pk2(a0.z + p0.z, a0.w + p0.w);
        us.z = pk2(a1.x + p1.x, a1.y + p1.y); us.w = pk2(a1.z + p1.z, a1.w + p1.w);
        int ll = n + 16 * kg;
        ABf[0][nt][kt][ll] = ua;
        ABf[1][nt][kt][ll] = us;
    }
    __syncthreads();

    // ---- GEMM1: Hpr & Hpo
    {
        f32x4 accP[4][4], accQ[4][4];
        #pragma unroll
        for (int mt = 0; mt < 4; ++mt)
            #pragma unroll
            for (int nt = 0; nt < 4; ++nt) { accP[mt][nt] = (f32x4)0.f; accQ[mt][nt] = (f32x4)0.f; }
        for (int kt = 0; kt < 8; ++kt) {
            uint4 wa[4], bA[4], bS[4];
            #pragma unroll
            for (int mt = 0; mt < 4; ++mt)
                wa[mt] = ((const uint4*)W1A)[(size_t)((wv * 4 + mt) * 8 + kt) * 64 + l];
            #pragma unroll
            for (int nt = 0; nt < 4; ++nt) { bA[nt] = ABf[0][nt][kt][l]; bS[nt] = ABf[1][nt][kt][l]; }
            #pragma unroll
            for (int mt = 0; mt < 4; ++mt)
                #pragma unroll
                for (int nt = 0; nt < 4; ++nt) {
                    accP[mt][nt] = mfma16(wa[mt], bA[nt], accP[mt][nt]);
                    accQ[mt][nt] = mfma16(wa[mt], bS[nt], accQ[mt][nt]);
                }
        }
        #pragma unroll
        for (int mt = 0; mt < 4; ++mt) {
            int c0 = wv * 64 + mt * 16 + 4 * lg;
            float4 bv = *(const float4*)&bd1[c0];
            #pragma unroll
            for (int nt = 0; nt < 4; ++nt) {
                size_t o = (size_t)(base + nt * 16 + lr) * H_DIM + c0;
                uint2 wp, wq;
                wp.x = pk2(accP[mt][nt][0] + bv.x, accP[mt][nt][1] + bv.y);
                wp.y = pk2(accP[mt][nt][2] + bv.z, accP[mt][nt][3] + bv.w);
                wq.x = pk2(accQ[mt][nt][0] + bv.x, accQ[mt][nt][1] + bv.y);
                wq.y = pk2(accQ[mt][nt][2] + bv.z, accQ[mt][nt][3] + bv.w);
                *(uint2*)&HprF[o] = wp;
                *(uint2*)&HpoF[o] = wq;
            }
        }
    }

    // ---- GEMM2: Hp
    {
        f32x4 accH[4][4];
        #pragma unroll
        for (int mt = 0; mt < 4; ++mt)
            #pragma unroll
            for (int nt = 0; nt < 4; ++nt) accH[mt][nt] = (f32x4)0.f;
        for (int kt = 0; kt < 8; ++kt) {
            uint4 wa[4], bA[4];
            #pragma unroll
            for (int mt = 0; mt < 4; ++mt)
                wa[mt] = ((const uint4*)WP1A)[(size_t)((wv * 4 + mt) * 8 + kt) * 64 + l];
            #pragma unroll
            for (int nt = 0; nt < 4; ++nt) bA[nt] = ABf[0][nt][kt][l];
            #pragma unroll
            for (int mt = 0; mt < 4; ++mt)
                #pragma unroll
                for (int nt = 0; nt < 4; ++nt) accH[mt][nt] = mfma16(wa[mt], bA[nt], accH[mt][nt]);
        }
        #pragma unroll
        for (int mt = 0; mt < 4; ++mt) {
            int c0 = wv * 64 + mt * 16 + 4 * lg;
            float4 bv = *(const float4*)&bp1[c0];
            #pragma unroll
            for (int nt = 0; nt < 4; ++nt) {
                size_t o = (size_t)(base + nt * 16 + lr) * H_DIM + c0;
                uint2 wp;
                wp.x = pk2(accH[mt][nt][0] + bv.x, accH[mt][nt][1] + bv.y);
                wp.y = pk2(accH[mt][nt][2] + bv.z, accH[mt][nt][3] + bv.w);
                *(uint2*)&HpF[o] = wp;
            }
        }
    }

    // ---- GEMM3: fh
    {
        f32x4 accF[4][4];
        #pragma unroll
        for (int mt = 0; mt < 4; ++mt)
            #pragma unroll
            for (int nt = 0; nt < 4; ++nt) accF[mt][nt] = (f32x4)0.f;
        for (int kt = 0; kt < 8; ++kt) {
            uint4 wa[4], bA[4];
            #pragma unroll
            for (int mt = 0; mt < 4; ++mt)
                wa[mt] = ((const uint4*)WF1)[(size_t)((wv * 4 + mt) * 8 + kt) * 64 + l];
            #pragma unroll
            for (int nt = 0; nt < 4; ++nt) bA[nt] = ABf[0][nt][kt][l];
            #pragma unroll
            for (int mt = 0; mt < 4; ++mt)
                #pragma unroll
                for (int nt = 0; nt < 4; ++nt) accF[mt][nt] = mfma16(wa[mt], bA[nt], accF[mt][nt]);
        }
        #pragma unroll
        for (int mt = 0; mt < 4; ++mt) {
            int c0 = wv * 64 + mt * 16 + 4 * lg;
            float4 bv = *(const float4*)&bf1[c0];
            int kt2 = c0 >> 5;
            int l2  = lr + 16 * ((c0 >> 3) & 3);
            int half = (c0 & 7) >> 2;
            #pragma unroll
            for (int nt = 0; nt < 4; ++nt) {
                uint2 wp;
                wp.x = pk2(fmaxf(accF[mt][nt][0] + bv.x, 0.f), fmaxf(accF[mt][nt][1] + bv.y, 0.f));
                wp.y = pk2(fmaxf(accF[mt][nt][2] + bv.z, 0.f), fmaxf(accF[mt][nt][3] + bv.w, 0.f));
                ((uint2*)&FHf[nt][kt2][l2])[half] = wp;
            }
        }
    }
    __syncthreads();

    // ---- GEMM4: Diff
    {
        f32x4 accD[4];
        #pragma unroll
        for (int nt = 0; nt < 4; ++nt) accD[nt] = (f32x4)0.f;
        for (int kt = 0; kt < 16; ++kt) {
            uint4 wf = ((const uint4*)WF2)[(size_t)(wv * 16 + kt) * 64 + l];
            #pragma unroll
            for (int nt = 0; nt < 4; ++nt) accD[nt] = mfma16(wf, FHf[nt][kt][l], accD[nt]);
        }
        int c0 = wv * 16 + 4 * lg;
        float4 bv = *(const float4*)&bf2[c0];
        #pragma unroll
        for (int nt = 0; nt < 4; ++nt) {
            float4 o;
            o.x = __expf(accD[nt][0] + bv.x);
            o.y = __expf(accD[nt][1] + bv.y);
            o.z = __expf(accD[nt][2] + bv.z);
            o.w = __expf(accD[nt][3] + bv.w);
            *(float4*)&Diff[(size_t)(base + nt * 16 + lr) * Z_DIM + c0] = o;
        }
    }
}

// ---------------------------------------------------------------------------
// K2: MFMA scan, N=16 packed. 64 blocks x 512 threads (8 waves).
// Block bk owns 16 rows: row = bk*16 + n, n = lr; b = bk*2 + (n>>3), s = n&7.
// Phase A: wave wv -> H-cols [wv*64, +64) (4 M-tiles).  All frags dense.
// Phase B: wave wv -> z-cols [wv*16, +16); computes BOTH P and Q (shared wb).
// Weights pinned in AGPRs (KEEPA each iteration). 2 barriers/t.
// ---------------------------------------------------------------------------
__global__ __launch_bounds__(512, 1) void k2_scan(
    const f16* __restrict__ WA, const f16* __restrict__ WB,
    const f16* __restrict__ HprF, const f16* __restrict__ HpoF,
    const float* __restrict__ Diff, const float* __restrict__ noise,
    const float* __restrict__ bd2,
    const float* __restrict__ z_state, unsigned* __restrict__ ztraj_u,
    float* __restrict__ out_z, float* __restrict__ loss_acc)
{
    const int bk = blockIdx.x;              // [0,64)
    const int tid = threadIdx.x;
    const int wv = tid >> 6, l = tid & 63;
    const int lr = l & 15, lg = l >> 4;
    const int b   = bk * 2 + (lr >> 3);     // batch for this lane's column n=lr
    const int row = bk * 16 + lr;           // global row in [0,1024)

    __shared__ u32x4 zfrag[4][64];          // 4 KB
    __shared__ u32x4 phfrag[16][64];        // 16 KB
    __shared__ u32x4 qhfrag[16][64];        // 16 KB
    __shared__ float red2[512];

    // ---- weights -> registers (pinned to AGPR file)
    u32x4 wa[4][4];
    #pragma unroll
    for (int mt = 0; mt < 4; ++mt)
        #pragma unroll
        for (int kt = 0; kt < 4; ++kt)
            wa[mt][kt] = ((const u32x4*)WA)[(size_t)((wv * 4 + mt) * 4 + kt) * 64 + l];
    u32x4 wb[16];
    #pragma unroll
    for (int kt = 0; kt < 16; ++kt)
        wb[kt] = ((const u32x4*)WB)[(size_t)(wv * 16 + kt) * 64 + l];

    // ---- per-lane state: z cols [j0, j0+4) of row n=lr
    const int j0 = wv * 16 + 4 * lg;
    float zreg[4], bdv[4];
    *(float4*)zreg = *(const float4*)&z_state[(size_t)row * Z_DIM + j0];
    *(float4*)bdv  = *(const float4*)&bd2[j0];
    // zfrag slot for (j0.., n=lr):
    uint2* zslot = ((uint2*)&zfrag[wv >> 1][lr + 16 * (2 * (wv & 1) + (lg >> 1))]) + (lg & 1);
    {
        uint2 zz; zz.x = pk2(zreg[0], zreg[1]); zz.y = pk2(zreg[2], zreg[3]);
        *zslot = zz;
    }

    // ---- prefetch t=0 streams (all lanes)
    uint2 hp[4], hq[4];
    float4 dif, ep;
    {
        size_t hb0 = (size_t)b * H_DIM;
        #pragma unroll
        for (int mt = 0; mt < 4; ++mt) {
            int c0 = wv * 64 + mt * 16 + 4 * lg;
            hp[mt] = *(const uint2*)&HprF[hb0 + c0];
            hq[mt] = *(const uint2*)&HpoF[hb0 + c0];
        }
        dif = *(const float4*)&Diff[(size_t)b * Z_DIM + j0];
        ep  = *(const float4*)&noise[(size_t)row * Z_DIM + j0];
    }
    __syncthreads();

    float kacc = 0.f;

    for (int t = 0; t < T_DIM; ++t) {
        // pin weights every iteration (prevents remat-from-L2)
        #pragma unroll
        for (int mt = 0; mt < 4; ++mt)
            #pragma unroll
            for (int kt = 0; kt < 4; ++kt) KEEPA(wa[mt][kt]);
        #pragma unroll
        for (int kt = 0; kt < 16; ++kt) KEEPA(wb[kt]);

        // -------- phase A: G^T = Wd1z^T @ z^T -> ph/qh frags (all lanes real)
        u32x4 zb[4];
        #pragma unroll
        for (int kt = 0; kt < 4; ++kt) zb[kt] = zfrag[kt][l];
        #pragma unroll
        for (int mt = 0; mt < 4; ++mt) {
            f32x4 acc = (f32x4)0.f;
            #pragma unroll
            for (int kt = 0; kt < 4; ++kt) acc = mfma16v(wa[mt][kt], zb[kt], acc);
            fp16x2 zero2 = {(__fp16)0.f, (__fp16)0.f};
            fp16x2 a01 = __builtin_amdgcn_cvt_pkrtz(acc[0], acc[1]);
            fp16x2 a23 = __builtin_amdgcn_cvt_pkrtz(acc[2], acc[3]);
            fp16x2 p01 = __builtin_elementwise_max(a01 + __builtin_bit_cast(fp16x2, hp[mt].x), zero2);
            fp16x2 p23 = __builtin_elementwise_max(a23 + __builtin_bit_cast(fp16x2, hp[mt].y), zero2);
            fp16x2 q01 = __builtin_elementwise_max(a01 + __builtin_bit_cast(fp16x2, hq[mt].x), zero2);
            fp16x2 q23 = __builtin_elementwise_max(a23 + __builtin_bit_cast(fp16x2, hq[mt].y), zero2);
            int c0 = wv * 64 + mt * 16 + 4 * lg;
            int ktp = c0 >> 5;
            int l2  = lr + 16 * ((c0 >> 3) & 3);
            int half = (c0 & 7) >> 2;      // = lg&1
            uint2 wp, wq;
            wp.x = __builtin_bit_cast(unsigned, p01); wp.y = __builtin_bit_cast(unsigned, p23);
            wq.x = __builtin_bit_cast(unsigned, q01); wq.y = __builtin_bit_cast(unsigned, q23);
            ((uint2*)&phfrag[ktp][l2])[half] = wp;
            ((uint2*)&qhfrag[ktp][l2])[half] = wq;
        }

        // -------- prefetch t+1 streams (in flight across barrier + phase B)
        int tn = (t + 1 < T_DIM) ? (t + 1) : t;
        uint2 hpn[4], hqn[4];
        float4 difn, epn;
        {
            size_t hbn = ((size_t)tn * B_DIM + b) * H_DIM;
            #pragma unroll
            for (int mt = 0; mt < 4; ++mt) {
                int c0 = wv * 64 + mt * 16 + 4 * lg;
                hpn[mt] = *(const uint2*)&HprF[hbn + c0];
                hqn[mt] = *(const uint2*)&HpoF[hbn + c0];
            }
            difn = *(const float4*)&Diff[((size_t)tn * B_DIM + b) * Z_DIM + j0];
            epn  = *(const float4*)&noise[((size_t)tn * 1024 + row) * Z_DIM + j0];
        }
        __syncthreads();

        // -------- phase B: P^T & Q^T = Wd2^T @ {ph,qh}^T (wave owns 16 z-cols)
        f32x4 aP = (f32x4)0.f, aQ = (f32x4)0.f;
        #pragma unroll
        for (int kt = 0; kt < 16; ++kt) {
            u32x4 pb = phfrag[kt][l];
            u32x4 qb = qhfrag[kt][l];
            aP = mfma16v(wb[kt], pb, aP);
            aQ = mfma16v(wb[kt], qb, aQ);
        }
        {
            const float* difp = (const float*)&dif;
            const float* epp  = (const float*)&ep;
            #pragma unroll
            for (int i = 0; i < 4; ++i) {
                float pr = 0.1f * tanh_fast(aP[i] + bdv[i]);
                float po = 0.1f * tanh_fast(aQ[i] + bdv[i]);
                float dv = difp[i];
                zreg[i] = zreg[i] + DT_F * po + SQRT_DT_F * dv * epp[i];
                float e = (pr - po) * rcp_fast(dv);
                kacc = fmaf(e, e, kacc);
            }
            uint2 zz; zz.x = pk2(zreg[0], zreg[1]); zz.y = pk2(zreg[2], zreg[3]);
            *zslot = zz;
            *(uint2*)&ztraj_u[((size_t)t * 1024 + row) * 64 + (j0 >> 1)] = zz;
        }
        // rotate prefetch
        #pragma unroll
        for (int mt = 0; mt < 4; ++mt) { hp[mt] = hpn[mt]; hq[mt] = hqn[mt]; }
        dif = difn; ep = epn;
        __syncthreads();
    }

    // ---- final z out
    *(float4*)&out_z[(size_t)row * Z_DIM + j0] = *(const float4*)zreg;

    // ---- kld reduce
    red2[tid] = kacc;
    __syncthreads();
    for (int st = 256; st > 0; st >>= 1) {
        if (tid < st) red2[tid] += red2[tid + st];
        __syncthreads();
    }
    if (tid == 0) atomicAdd(loss_acc + 0, red2[0]);
}

// ---------------------------------------------------------------------------
// K3: recon (phases C/D), fully parallel over (t,b,s). 4096 blocks x 512 thr.
// ---------------------------------------------------------------------------
__global__ __launch_bounds__(512, 2) void k3_recon(
    const f16* __restrict__ WC, const f16* __restrict__ WD,
    const f16* __restrict__ HpF, const unsigned* __restrict__ ztraj_u,
    const float* __restrict__ X, const float* __restrict__ MtM,
    const float* __restrict__ bp2, float* __restrict__ loss_acc)
{
    const int t  = blockIdx.x >> 5;
    const int b0 = (blockIdx.x & 31) * 4;
    const int tid = threadIdx.x;
    const int wv = tid >> 6, l = tid & 63;
    const int lr = l & 15, lg = l >> 4;

    __shared__ uint4 zfrag[4][2][64];
    __shared__ uint4 pwfrag[16][2][64];
    __shared__ float obuf[128][33];
    __shared__ float red2[512];

    uint4 wc[4][4];
    #pragma unroll
    for (int mt = 0; mt < 4; ++mt)
        #pragma unroll
        for (int kt = 0; kt < 4; ++kt)
            wc[mt][kt] = ((const uint4*)WC)[(size_t)((wv * 4 + mt) * 4 + kt) * 64 + l];
    uint4 wd[16];
    #pragma unroll
    for (int kt = 0; kt < 16; ++kt)
        wd[kt] = ((const uint4*)WD)[(size_t)(wv * 16 + kt) * 64 + l];

    {
        int kt = tid >> 7;
        int nt = (tid >> 6) & 1;
        int ll = tid & 63;
        int n = ll & 15, kg = ll >> 4;
        int rl = nt * 16 + n;
        size_t grow = (size_t)t * 1024 + (size_t)b0 * S_DIM + rl;
        zfrag[kt][nt][ll] = *(const uint4*)&ztraj_u[grow * 64 + kt * 16 + kg * 4];
    }
    __syncthreads();

    f16* pwf = (f16*)pwfrag;
    #pragma unroll
    for (int nt = 0; nt < 2; ++nt) {
        #pragma unroll
        for (int mt = 0; mt < 4; ++mt) {
            f32x4 acc = (f32x4)0.f;
            #pragma unroll
            for (int kt = 0; kt < 4; ++kt) acc = mfma16(wc[mt][kt], zfrag[kt][nt][l], acc);
            int c0 = wv * 64 + mt * 16 + 4 * lg;
            int rl = nt * 16 + lr;
            int bb = b0 + (rl >> 3);
            size_t hbs = ((size_t)t * B_DIM + bb) * H_DIM;
            uint2 hpv = *(const uint2*)&HpF[hbs + c0];
            float p0 = fmaxf(acc[0] + upk_lo(hpv.x), 0.f);
            float p1 = fmaxf(acc[1] + upk_hi(hpv.x), 0.f);
            float p2 = fmaxf(acc[2] + upk_lo(hpv.y), 0.f);
            float p3 = fmaxf(acc[3] + upk_hi(hpv.y), 0.f);
            int ktp = c0 >> 5;
            int lp  = lr + 16 * ((c0 >> 3) & 3);
            int off = c0 & 7;
            uint2 wp; wp.x = pk2(p0, p1); wp.y = pk2(p2, p3);
            *(uint2*)&pwf[(size_t)((ktp * 2 + nt) * 64 + lp) * 8 + off] = wp;
        }
    }
    __syncthreads();

    #pragma unroll
    for (int nt = 0; nt < 2; ++nt) {
        f32x4 acc = (f32x4)0.f;
        #pragma unroll
        for (int kt = 0; kt < 16; ++kt) acc = mfma16(wd[kt], pwfrag[kt][nt][l], acc);
        int m0 = wv * 16 + 4 * lg;
        int row = nt * 16 + lr;
        #pragma unroll
        for (int i = 0; i < 4; ++i) obuf[m0 + i][row] = acc[i];
    }
    __syncthreads();

    float racc = 0.f;
    {
        int row = tid >> 4;
        int d4 = (tid & 15) * 4;
        int bb = b0 + (row >> 3);
        float mt = MtM[(size_t)t * B_DIM + bb];
        #pragma unroll
        for (int i = 0; i < 4; ++i) {
            int d = d4 + i;
            float mean = obuf[d][row] + bp2[d];
            float lv   = obuf[d + 64][row] + bp2[64 + d];
            float xv = X[((size_t)t * B_DIM + bb) * DIN + d];
            float dm = xv - mean;
            float nll = 0.5f * (LOG_2PI_F + lv + dm * dm * __expf(-lv));
            racc = fmaf(mt, nll, racc);
        }
    }
    red2[tid] = racc;
    __syncthreads();
    for (int st = 256; st > 0; st >>= 1) {
        if (tid < st) red2[tid] += red2[tid + st];
        __syncthreads();
    }
    if (tid == 0) atomicAdd(loss_acc + 1, red2[0]);
}

// ---------------------------------------------------------------------------
// K4: finalize
// ---------------------------------------------------------------------------
__global__ void k4_final(const float* __restrict__ loss_acc, float* __restrict__ out)
{
    if (threadIdx.x == 0 && blockIdx.x == 0) {
        float kld   = loss_acc[0] * (0.5f * DT_F / (float)(B_DIM * S_DIM));
        float recon = loss_acc[1] * (1.0f / (float)(B_DIM * S_DIM));
        out[131072] = recon + kld;
        out[131073] = recon;
        out[131074] = kld;
    }
}

// ---------------------------------------------------------------------------
extern "C" void kernel_launch(void* const* d_in, const int* in_sizes, int n_in,
                              void* d_out, int out_size, void* d_ws, size_t ws_size,
                              hipStream_t stream)
{
    const float* X        = (const float*)d_in[0];
    const float* M        = (const float*)d_in[1];
    const float* cov      = (const float*)d_in[2];
    const float* path_h   = (const float*)d_in[3];
    const float* path_hpos= (const float*)d_in[4];
    const float* noise    = (const float*)d_in[5];
    const float* Wc1 = (const float*)d_in[6];
    const float* bc1 = (const float*)d_in[7];
    const float* Wc2 = (const float*)d_in[8];
    const float* bc2 = (const float*)d_in[9];
    const float* Wd1 = (const float*)d_in[10];
    const float* bd1 = (const float*)d_in[11];
    const float* Wd2 = (const float*)d_in[12];
    const float* bd2 = (const float*)d_in[13];
    const float* Wf1 = (const float*)d_in[14];
    const float* bf1 = (const float*)d_in[15];
    const float* Wf2 = (const float*)d_in[16];
    const float* bf2 = (const float*)d_in[17];
    const float* Wp1 = (const float*)d_in[18];
    const float* bp1 = (const float*)d_in[19];
    const float* Wp2 = (const float*)d_in[20];
    const float* bp2 = (const float*)d_in[21];
    float* out = (float*)d_out;

    // workspace layout (bytes, 256-aligned)
    char* ws = (char*)d_ws;
    size_t o = 0;
    float* z_state = (float*)(ws + o); o += 524288;
    float* loss    = (float*)(ws + o); o += 256;
    f16* WA   = (f16*)(ws + o); o += 131072;
    f16* WB   = (f16*)(ws + o); o += 131072;
    f16* WC   = (f16*)(ws + o); o += 131072;
    f16* WD   = (f16*)(ws + o); o += 131072;
    f16* W1A  = (f16*)(ws + o); o += 262144;
    f16* WF1  = (f16*)(ws + o); o += 262144;
    f16* WP1A = (f16*)(ws + o); o += 262144;
    f16* WF2  = (f16*)(ws + o); o += 131072;
    f16* HprF = (f16*)(ws + o); o += 16777216;
    f16* HpoF = (f16*)(ws + o); o += 16777216;
    f16* HpF  = (f16*)(ws + o); o += 16777216;
    float* Diff = (float*)(ws + o); o += 8388608;
    float* MtM  = (float*)(ws + o); o += 65536;
    unsigned* ztraj = (unsigned*)(ws + o); o += 33554432;

    kw_frag<<<2816, 256, 0, stream>>>(Wd1, Wd2, Wp1, Wp2, Wf1, Wf2,
                                      WA, WB, WC, WD, W1A, WF1, WP1A, WF2);
    k0_init<<<B_DIM, 128, 0, stream>>>(cov, Wc1, bc1, Wc2, bc2, z_state, loss);
    k1_pre<<<256, 512, 0, stream>>>(path_h, path_hpos, M,
                                    W1A, WF1, WP1A, WF2,
                                    bd1, bf1, bf2, bp1,
                                    HprF, HpoF, HpF, Diff, MtM);
    k2_scan<<<64, 512, 0, stream>>>(WA, WB, HprF, HpoF, Diff, noise, bd2,
                                    z_state, ztraj, out, loss);
    k3_recon<<<4096, 512, 0, stream>>>(WC, WD, HpF, ztraj, X, MtM, bp2, loss);
    k4_final<<<1, 64, 0, stream>>>(loss, out);
}

// Round 7
// 530.534 us; speedup vs baseline: 16.5506x; 1.0474x over previous
//
#include <hip/hip_runtime.h>
#include <hip/hip_bf16.h>
#include <math.h>

// Problem dims (fixed by setup_inputs)
#define T_DIM 128
#define B_DIM 128
#define S_DIM 8
#define DIN   64
#define R_DIM 256
#define Z_DIM 128
#define H_DIM 512
#define C_DIM 32
#define CH_DIM 64

#define DT_F      0.05f
#define SQRT_DT_F 0.22360679774997896f
#define LOG_2PI_F 1.8378770664093453f

typedef _Float16 f16;
typedef __fp16 fp16x2 __attribute__((ext_vector_type(2)));
typedef _Float16 f16x8 __attribute__((ext_vector_type(8)));
typedef float f32x4 __attribute__((ext_vector_type(4)));
typedef unsigned u32x4 __attribute__((ext_vector_type(4)));

union U16x8 { uint4 u; f16x8 h; };

__device__ __forceinline__ f32x4 mfma16(const uint4& a, const uint4& b, f32x4 c) {
    U16x8 ua, ub; ua.u = a; ub.u = b;
    return __builtin_amdgcn_mfma_f32_16x16x32_f16(ua.h, ub.h, c, 0, 0, 0);
}

__device__ __forceinline__ f32x4 mfma16v(u32x4 a, u32x4 b, f32x4 c) {
    return __builtin_amdgcn_mfma_f32_16x16x32_f16(
        __builtin_bit_cast(f16x8, a), __builtin_bit_cast(f16x8, b), c, 0, 0, 0);
}

#define KEEPV(x) asm volatile("" : "+v"(x))

__device__ __forceinline__ unsigned pk2(float a, float b) {
    fp16x2 h = __builtin_amdgcn_cvt_pkrtz(a, b);
    return __builtin_bit_cast(unsigned, h);
}
__device__ __forceinline__ float upk_lo(unsigned u) {
    return (float)__builtin_bit_cast(f16, (unsigned short)(u & 0xffffu));
}
__device__ __forceinline__ float upk_hi(unsigned u) {
    return (float)__builtin_bit_cast(f16, (unsigned short)(u >> 16));
}

__device__ __forceinline__ float rcp_fast(float x) {
    return __builtin_amdgcn_rcpf(x);
}

__device__ __forceinline__ float tanh_fast(float x) {
    float ax = fabsf(x);
    float e  = __expf(-2.0f * ax);
    float r  = (1.0f - e) * rcp_fast(1.0f + e);
    return copysignf(r, x);
}

// ---------------------------------------------------------------------------
// KW: pre-fragment weights into MFMA A-frag layouts (f16).
// ---------------------------------------------------------------------------
__global__ __launch_bounds__(256) void kw_frag(
    const float* __restrict__ Wd1, const float* __restrict__ Wd2,
    const float* __restrict__ Wp1, const float* __restrict__ Wp2,
    const float* __restrict__ Wf1, const float* __restrict__ Wf2,
    f16* __restrict__ WA, f16* __restrict__ WB,
    f16* __restrict__ WC, f16* __restrict__ WD,
    f16* __restrict__ W1A, f16* __restrict__ WF1,
    f16* __restrict__ WP1A, f16* __restrict__ WF2)
{
    int gid = blockIdx.x * 256 + threadIdx.x;    // [0, 720896)
    const float* W; f16* dst; int k0, nktl, ld, off;
    if      (gid < 65536)  { W = Wd1; dst = WA;   k0 = 256; nktl = 2; ld = 512; off = gid; }
    else if (gid < 131072) { W = Wd2; dst = WB;   k0 = 0;   nktl = 4; ld = 128; off = gid - 65536; }
    else if (gid < 196608) { W = Wp1; dst = WC;   k0 = 256; nktl = 2; ld = 512; off = gid - 131072; }
    else if (gid < 262144) { W = Wp2; dst = WD;   k0 = 0;   nktl = 4; ld = 128; off = gid - 196608; }
    else if (gid < 393216) { W = Wd1; dst = W1A;  k0 = 0;   nktl = 3; ld = 512; off = gid - 262144; }
    else if (gid < 524288) { W = Wf1; dst = WF1;  k0 = 0;   nktl = 3; ld = 512; off = gid - 393216; }
    else if (gid < 655360) { W = Wp1; dst = WP1A; k0 = 0;   nktl = 3; ld = 512; off = gid - 524288; }
    else                   { W = Wf2; dst = WF2;  k0 = 0;   nktl = 4; ld = 128; off = gid - 655360; }
    int j = off & 7, l = (off >> 3) & 63, tile = off >> 9;
    int mt = tile >> nktl, kt = tile & ((1 << nktl) - 1);
    int lr = l & 15, lg = l >> 4;
    int c = mt * 16 + lr;
    int k = k0 + kt * 32 + 8 * lg + j;
    dst[off] = (f16)W[(size_t)k * ld + c];
}

// ---------------------------------------------------------------------------
// K0: z0 = tanh(mlp(cov)); zero loss accumulators.
// ---------------------------------------------------------------------------
__global__ __launch_bounds__(128) void k0_init(
    const float* __restrict__ cov,
    const float* __restrict__ Wc1, const float* __restrict__ bc1,
    const float* __restrict__ Wc2, const float* __restrict__ bc2,
    float* __restrict__ z_state, float* __restrict__ loss_acc)
{
    int b = blockIdx.x;
    int tid = threadIdx.x;
    __shared__ float covs[C_DIM];
    __shared__ float hid[CH_DIM];
    if (tid < C_DIM) covs[tid] = cov[b * C_DIM + tid];
    __syncthreads();
    if (tid < CH_DIM) {
        float a = bc1[tid];
        #pragma unroll
        for (int c = 0; c < C_DIM; ++c) a = fmaf(covs[c], Wc1[c * CH_DIM + tid], a);
        hid[tid] = fmaxf(a, 0.0f);
    }
    __syncthreads();
    float a = bc2[tid];
    #pragma unroll 8
    for (int h = 0; h < CH_DIM; ++h) a = fmaf(hid[h], Wc2[h * Z_DIM + tid], a);
    float z0 = tanh_fast(a);
    #pragma unroll
    for (int s = 0; s < S_DIM; ++s)
        z_state[((size_t)b * S_DIM + s) * Z_DIM + tid] = z0;
    if (b == 0 && tid < 2) loss_acc[tid] = 0.0f;
}

// ---------------------------------------------------------------------------
// K1 (MFMA): per block 64 rows, 8 waves. Unchanged (passed).
// ---------------------------------------------------------------------------
__global__ __launch_bounds__(512, 1) void k1_pre(
    const float* __restrict__ path_h, const float* __restrict__ path_hpos,
    const float* __restrict__ M,
    const f16* __restrict__ W1A, const f16* __restrict__ WF1,
    const f16* __restrict__ WP1A, const f16* __restrict__ WF2,
    const float* __restrict__ bd1, const float* __restrict__ bf1,
    const float* __restrict__ bf2, const float* __restrict__ bp1,
    f16* __restrict__ HprF, f16* __restrict__ HpoF, f16* __restrict__ HpF,
    float* __restrict__ Diff, float* __restrict__ MtM)
{
    const int base = blockIdx.x * 64;
    const int tid = threadIdx.x;
    const int wv = tid >> 6, l = tid & 63;
    const int lr = l & 15, lg = l >> 4;

    __shared__ uint4 ABf[2][4][8][64];
    __shared__ uint4 FHf[4][16][64];

    {
        int row = base + (tid >> 3), sg = tid & 7;
        const float4* mp = (const float4*)(M + (size_t)row * DIN + sg * 8);
        float4 m0 = mp[0], m1 = mp[1];
        float sm = m0.x + m0.y + m0.z + m0.w + m1.x + m1.y + m1.z + m1.w;
        sm += __shfl_xor(sm, 1);
        sm += __shfl_xor(sm, 2);
        sm += __shfl_xor(sm, 4);
        if (sg == 0) MtM[row] = sm * (1.0f / 64.0f);
    }

    for (int it = 0; it < 4; ++it) {
        int s = it * 512 + tid;
        int ktkg = s & 31, n = (s >> 5) & 15, nt = s >> 9;
        int kt = ktkg >> 2, kg = ktkg & 3;
        int row = base + nt * 16 + n;
        const float4* ph4 = (const float4*)(path_h    + (size_t)row * R_DIM + kt * 32 + kg * 8);
        const float4* pp4 = (const float4*)(path_hpos + (size_t)row * R_DIM + kt * 32 + kg * 8);
        float4 a0 = ph4[0], a1 = ph4[1];
        float4 p0 = pp4[0], p1 = pp4[1];
        uint4 ua, us;
        ua.x = pk2(a0.x, a0.y); ua.y = pk2(a0.z, a0.w);
        ua.z = pk2(a1.x, a1.y); ua.w = pk2(a1.z, a1.w);
        us.x = pk2(a0.x + p0.x, a0.y + p0.y); us.y = pk2(a0.z + p0.z, a0.w + p0.w);
        us.z = pk2(a1.x + p1.x, a1.y + p1.y); us.w = pk2(a1.z + p1.z, a1.w + p1.w);
        int ll = n + 16 * kg;
        ABf[0][nt][kt][ll] = ua;
        ABf[1][nt][kt][ll] = us;
    }
    __syncthreads();

    // ---- GEMM1: Hpr & Hpo
    {
        f32x4 accP[4][4], accQ[4][4];
        #pragma unroll
        for (int mt = 0; mt < 4; ++mt)
            #pragma unroll
            for (int nt = 0; nt < 4; ++nt) { accP[mt][nt] = (f32x4)0.f; accQ[mt][nt] = (f32x4)0.f; }
        for (int kt = 0; kt < 8; ++kt) {
            uint4 wa[4], bA[4], bS[4];
            #pragma unroll
            for (int mt = 0; mt < 4; ++mt)
                wa[mt] = ((const uint4*)W1A)[(size_t)((wv * 4 + mt) * 8 + kt) * 64 + l];
            #pragma unroll
            for (int nt = 0; nt < 4; ++nt) { bA[nt] = ABf[0][nt][kt][l]; bS[nt] = ABf[1][nt][kt][l]; }
            #pragma unroll
            for (int mt = 0; mt < 4; ++mt)
                #pragma unroll
                for (int nt = 0; nt < 4; ++nt) {
                    accP[mt][nt] = mfma16(wa[mt], bA[nt], accP[mt][nt]);
                    accQ[mt][nt] = mfma16(wa[mt], bS[nt], accQ[mt][nt]);
                }
        }
        #pragma unroll
        for (int mt = 0; mt < 4; ++mt) {
            int c0 = wv * 64 + mt * 16 + 4 * lg;
            float4 bv = *(const float4*)&bd1[c0];
            #pragma unroll
            for (int nt = 0; nt < 4; ++nt) {
                size_t o = (size_t)(base + nt * 16 + lr) * H_DIM + c0;
                uint2 wp, wq;
                wp.x = pk2(accP[mt][nt][0] + bv.x, accP[mt][nt][1] + bv.y);
                wp.y = pk2(accP[mt][nt][2] + bv.z, accP[mt][nt][3] + bv.w);
                wq.x = pk2(accQ[mt][nt][0] + bv.x, accQ[mt][nt][1] + bv.y);
                wq.y = pk2(accQ[mt][nt][2] + bv.z, accQ[mt][nt][3] + bv.w);
                *(uint2*)&HprF[o] = wp;
                *(uint2*)&HpoF[o] = wq;
            }
        }
    }

    // ---- GEMM2: Hp
    {
        f32x4 accH[4][4];
        #pragma unroll
        for (int mt = 0; mt < 4; ++mt)
            #pragma unroll
            for (int nt = 0; nt < 4; ++nt) accH[mt][nt] = (f32x4)0.f;
        for (int kt = 0; kt < 8; ++kt) {
            uint4 wa[4], bA[4];
            #pragma unroll
            for (int mt = 0; mt < 4; ++mt)
                wa[mt] = ((const uint4*)WP1A)[(size_t)((wv * 4 + mt) * 8 + kt) * 64 + l];
            #pragma unroll
            for (int nt = 0; nt < 4; ++nt) bA[nt] = ABf[0][nt][kt][l];
            #pragma unroll
            for (int mt = 0; mt < 4; ++mt)
                #pragma unroll
                for (int nt = 0; nt < 4; ++nt) accH[mt][nt] = mfma16(wa[mt], bA[nt], accH[mt][nt]);
        }
        #pragma unroll
        for (int mt = 0; mt < 4; ++mt) {
            int c0 = wv * 64 + mt * 16 + 4 * lg;
            float4 bv = *(const float4*)&bp1[c0];
            #pragma unroll
            for (int nt = 0; nt < 4; ++nt) {
                size_t o = (size_t)(base + nt * 16 + lr) * H_DIM + c0;
                uint2 wp;
                wp.x = pk2(accH[mt][nt][0] + bv.x, accH[mt][nt][1] + bv.y);
                wp.y = pk2(accH[mt][nt][2] + bv.z, accH[mt][nt][3] + bv.w);
                *(uint2*)&HpF[o] = wp;
            }
        }
    }

    // ---- GEMM3: fh
    {
        f32x4 accF[4][4];
        #pragma unroll
        for (int mt = 0; mt < 4; ++mt)
            #pragma unroll
            for (int nt = 0; nt < 4; ++nt) accF[mt][nt] = (f32x4)0.f;
        for (int kt = 0; kt < 8; ++kt) {
            uint4 wa[4], bA[4];
            #pragma unroll
            for (int mt = 0; mt < 4; ++mt)
                wa[mt] = ((const uint4*)WF1)[(size_t)((wv * 4 + mt) * 8 + kt) * 64 + l];
            #pragma unroll
            for (int nt = 0; nt < 4; ++nt) bA[nt] = ABf[0][nt][kt][l];
            #pragma unroll
            for (int mt = 0; mt < 4; ++mt)
                #pragma unroll
                for (int nt = 0; nt < 4; ++nt) accF[mt][nt] = mfma16(wa[mt], bA[nt], accF[mt][nt]);
        }
        #pragma unroll
        for (int mt = 0; mt < 4; ++mt) {
            int c0 = wv * 64 + mt * 16 + 4 * lg;
            float4 bv = *(const float4*)&bf1[c0];
            int kt2 = c0 >> 5;
            int l2  = lr + 16 * ((c0 >> 3) & 3);
            int half = (c0 & 7) >> 2;
            #pragma unroll
            for (int nt = 0; nt < 4; ++nt) {
                uint2 wp;
                wp.x = pk2(fmaxf(accF[mt][nt][0] + bv.x, 0.f), fmaxf(accF[mt][nt][1] + bv.y, 0.f));
                wp.y = pk2(fmaxf(accF[mt][nt][2] + bv.z, 0.f), fmaxf(accF[mt][nt][3] + bv.w, 0.f));
                ((uint2*)&FHf[nt][kt2][l2])[half] = wp;
            }
        }
    }
    __syncthreads();

    // ---- GEMM4: Diff
    {
        f32x4 accD[4];
        #pragma unroll
        for (int nt = 0; nt < 4; ++nt) accD[nt] = (f32x4)0.f;
        for (int kt = 0; kt < 16; ++kt) {
            uint4 wf = ((const uint4*)WF2)[(size_t)(wv * 16 + kt) * 64 + l];
            #pragma unroll
            for (int nt = 0; nt < 4; ++nt) accD[nt] = mfma16(wf, FHf[nt][kt][l], accD[nt]);
        }
        int c0 = wv * 16 + 4 * lg;
        float4 bv = *(const float4*)&bf2[c0];
        #pragma unroll
        for (int nt = 0; nt < 4; ++nt) {
            float4 o;
            o.x = __expf(accD[nt][0] + bv.x);
            o.y = __expf(accD[nt][1] + bv.y);
            o.z = __expf(accD[nt][2] + bv.z);
            o.w = __expf(accD[nt][3] + bv.w);
            *(float4*)&Diff[(size_t)(base + nt * 16 + lr) * Z_DIM + c0] = o;
        }
    }
}

// ---------------------------------------------------------------------------
// K2: MFMA scan. 256 blocks x 512 threads (8 waves), 4 rows/block.
// amdgpu_waves_per_eu(2,2): VGPR budget 256 -> 128 weight VGPRs stay resident.
// Frag LDS slots swizzled: logical (kg,n) -> physical 20*kg+n (2-way banks).
// Owner lanes (lr<4) carry the 4 real rows; broadcast reads feed MFMA padding.
// ---------------------------------------------------------------------------
__global__ __launch_bounds__(512, 1) __attribute__((amdgpu_waves_per_eu(2, 2)))
void k2_scan(
    const f16* __restrict__ WA, const f16* __restrict__ WB,
    const f16* __restrict__ HprF, const f16* __restrict__ HpoF,
    const float* __restrict__ Diff, const float* __restrict__ noise,
    const float* __restrict__ bd2,
    const float* __restrict__ z_state, unsigned* __restrict__ ztraj_u,
    float* __restrict__ out_z, float* __restrict__ loss_acc)
{
    const int b  = blockIdx.x >> 1;
    const int sh = blockIdx.x & 1;
    const int tid = threadIdx.x;
    const int wv = tid >> 6, l = tid & 63;
    const int lr = l & 15, lg = l >> 4;
    const bool owner = (lr < 4);
    // broadcast-read physical slot for logical (kg=lg, n=lr&3)
    const int rslot = 20 * lg + (lr & 3);

    __shared__ u32x4 zfrag[4][64];          // 4 KB
    __shared__ u32x4 phfrag[16][64];        // 16 KB
    __shared__ u32x4 qhfrag[16][64];        // 16 KB
    __shared__ float red2[512];

    // ---- weights -> VGPR (resident under the 256-reg budget)
    u32x4 wa[4][4];
    #pragma unroll
    for (int mt = 0; mt < 4; ++mt)
        #pragma unroll
        for (int kt = 0; kt < 4; ++kt)
            wa[mt][kt] = ((const u32x4*)WA)[(size_t)((wv * 4 + mt) * 4 + kt) * 64 + l];
    u32x4 wb[16];
    #pragma unroll
    for (int kt = 0; kt < 16; ++kt)
        wb[kt] = ((const u32x4*)WB)[(size_t)(wv * 16 + kt) * 64 + l];
    #pragma unroll
    for (int mt = 0; mt < 4; ++mt)
        #pragma unroll
        for (int kt = 0; kt < 4; ++kt) KEEPV(wa[mt][kt]);
    #pragma unroll
    for (int kt = 0; kt < 16; ++kt) KEEPV(wb[kt]);

    // ---- owner state: z cols [j0, j0+4) of s-row srow
    const int j0 = wv * 16 + 4 * lg;
    const int srow = sh * 4 + lr;
    float zreg[4] = {0.f, 0.f, 0.f, 0.f};
    float bdv[4] = {0.f, 0.f, 0.f, 0.f};
    // z frag write slot: kt_z = wv>>1, kg_z = 2*(wv&1)+(lg>>1), phys 20*kg_z+lr
    uint2* zslot = ((uint2*)&zfrag[wv >> 1][20 * (2 * (wv & 1) + (lg >> 1)) + lr]) + (lg & 1);
    if (owner) {
        *(float4*)zreg = *(const float4*)&z_state[((size_t)b * S_DIM + srow) * Z_DIM + j0];
        *(float4*)bdv  = *(const float4*)&bd2[j0];
        uint2 zz; zz.x = pk2(zreg[0], zreg[1]); zz.y = pk2(zreg[2], zreg[3]);
        *zslot = zz;
    }

    // ---- prefetch t=0 streams (owner lanes)
    uint2 hp[4], hq[4];
    float4 dif, ep;
    if (owner) {
        #pragma unroll
        for (int mt = 0; mt < 4; ++mt) {
            int c0 = wv * 64 + mt * 16 + 4 * lg;
            hp[mt] = *(const uint2*)&HprF[(size_t)b * H_DIM + c0];
            hq[mt] = *(const uint2*)&HpoF[(size_t)b * H_DIM + c0];
        }
        dif = *(const float4*)&Diff[(size_t)b * Z_DIM + j0];
        ep  = *(const float4*)&noise[((size_t)b * S_DIM + srow) * Z_DIM + j0];
    }
    __syncthreads();

    float kacc = 0.f;

    for (int t = 0; t < T_DIM; ++t) {
        // -------- phase A: G^T = Wd1z^T @ z^T -> ph/qh frags
        u32x4 zb[4];
        #pragma unroll
        for (int kt = 0; kt < 4; ++kt) zb[kt] = zfrag[kt][rslot];
        #pragma unroll
        for (int mt = 0; mt < 4; ++mt) {
            f32x4 acc = (f32x4)0.f;
            #pragma unroll
            for (int kt = 0; kt < 4; ++kt) acc = mfma16v(wa[mt][kt], zb[kt], acc);
            if (owner) {
                fp16x2 zero2 = {(__fp16)0.f, (__fp16)0.f};
                fp16x2 a01 = __builtin_amdgcn_cvt_pkrtz(acc[0], acc[1]);
                fp16x2 a23 = __builtin_amdgcn_cvt_pkrtz(acc[2], acc[3]);
                fp16x2 p01 = __builtin_elementwise_max(a01 + __builtin_bit_cast(fp16x2, hp[mt].x), zero2);
                fp16x2 p23 = __builtin_elementwise_max(a23 + __builtin_bit_cast(fp16x2, hp[mt].y), zero2);
                fp16x2 q01 = __builtin_elementwise_max(a01 + __builtin_bit_cast(fp16x2, hq[mt].x), zero2);
                fp16x2 q23 = __builtin_elementwise_max(a23 + __builtin_bit_cast(fp16x2, hq[mt].y), zero2);
                int c0 = wv * 64 + mt * 16 + 4 * lg;
                int ktp = c0 >> 5;
                int kgw = (c0 >> 3) & 3;       // K-subgroup within frag
                int half = (c0 & 7) >> 2;      // = lg&1
                uint2 wp, wq;
                wp.x = __builtin_bit_cast(unsigned, p01); wp.y = __builtin_bit_cast(unsigned, p23);
                wq.x = __builtin_bit_cast(unsigned, q01); wq.y = __builtin_bit_cast(unsigned, q23);
                ((uint2*)&phfrag[ktp][20 * kgw + lr])[half] = wp;
                ((uint2*)&qhfrag[ktp][20 * kgw + lr])[half] = wq;
            }
        }

        // -------- prefetch t+1 streams (in flight across barrier + phase B)
        int tn = (t + 1 < T_DIM) ? (t + 1) : t;
        uint2 hpn[4], hqn[4];
        float4 difn, epn;
        if (owner) {
            size_t hbn = ((size_t)tn * B_DIM + b) * H_DIM;
            #pragma unroll
            for (int mt = 0; mt < 4; ++mt) {
                int c0 = wv * 64 + mt * 16 + 4 * lg;
                hpn[mt] = *(const uint2*)&HprF[hbn + c0];
                hqn[mt] = *(const uint2*)&HpoF[hbn + c0];
            }
            difn = *(const float4*)&Diff[((size_t)tn * B_DIM + b) * Z_DIM + j0];
            epn  = *(const float4*)&noise[(((size_t)tn * B_DIM + b) * S_DIM + srow) * Z_DIM + j0];
        }
        __syncthreads();

        // -------- phase B: P^T & Q^T = Wd2^T @ {ph,qh}^T; z update; kld
        f32x4 aP = (f32x4)0.f, aQ = (f32x4)0.f;
        #pragma unroll
        for (int kt = 0; kt < 16; ++kt) {
            u32x4 pb = phfrag[kt][rslot];
            u32x4 qb = qhfrag[kt][rslot];
            aP = mfma16v(wb[kt], pb, aP);
            aQ = mfma16v(wb[kt], qb, aQ);
        }
        if (owner) {
            const float* difp = (const float*)&dif;
            const float* epp  = (const float*)&ep;
            #pragma unroll
            for (int i = 0; i < 4; ++i) {
                float pr = 0.1f * tanh_fast(aP[i] + bdv[i]);
                float po = 0.1f * tanh_fast(aQ[i] + bdv[i]);
                float dv = difp[i];
                zreg[i] = zreg[i] + DT_F * po + SQRT_DT_F * dv * epp[i];
                float e = (pr - po) * rcp_fast(dv);
                kacc = fmaf(e, e, kacc);
            }
            uint2 zz; zz.x = pk2(zreg[0], zreg[1]); zz.y = pk2(zreg[2], zreg[3]);
            *zslot = zz;
            *(uint2*)&ztraj_u[((size_t)t * 1024 + (size_t)b * S_DIM + srow) * 64 + (j0 >> 1)] = zz;
        }
        // rotate prefetch
        #pragma unroll
        for (int mt = 0; mt < 4; ++mt) { hp[mt] = hpn[mt]; hq[mt] = hqn[mt]; }
        dif = difn; ep = epn;
        __syncthreads();
    }

    // ---- final z out
    if (owner)
        *(float4*)&out_z[((size_t)b * S_DIM + srow) * Z_DIM + j0] = *(const float4*)zreg;

    // ---- kld reduce
    red2[tid] = kacc;
    __syncthreads();
    for (int st = 256; st > 0; st >>= 1) {
        if (tid < st) red2[tid] += red2[tid + st];
        __syncthreads();
    }
    if (tid == 0) atomicAdd(loss_acc + 0, red2[0]);
}

// ---------------------------------------------------------------------------
// K3: recon (phases C/D), fully parallel over (t,b,s). 4096 blocks x 512 thr.
// ---------------------------------------------------------------------------
__global__ __launch_bounds__(512, 2) void k3_recon(
    const f16* __restrict__ WC, const f16* __restrict__ WD,
    const f16* __restrict__ HpF, const unsigned* __restrict__ ztraj_u,
    const float* __restrict__ X, const float* __restrict__ MtM,
    const float* __restrict__ bp2, float* __restrict__ loss_acc)
{
    const int t  = blockIdx.x >> 5;
    const int b0 = (blockIdx.x & 31) * 4;
    const int tid = threadIdx.x;
    const int wv = tid >> 6, l = tid & 63;
    const int lr = l & 15, lg = l >> 4;

    __shared__ uint4 zfrag[4][2][64];
    __shared__ uint4 pwfrag[16][2][64];
    __shared__ float obuf[128][33];
    __shared__ float red2[512];

    uint4 wc[4][4];
    #pragma unroll
    for (int mt = 0; mt < 4; ++mt)
        #pragma unroll
        for (int kt = 0; kt < 4; ++kt)
            wc[mt][kt] = ((const uint4*)WC)[(size_t)((wv * 4 + mt) * 4 + kt) * 64 + l];
    uint4 wd[16];
    #pragma unroll
    for (int kt = 0; kt < 16; ++kt)
        wd[kt] = ((const uint4*)WD)[(size_t)(wv * 16 + kt) * 64 + l];

    {
        int kt = tid >> 7;
        int nt = (tid >> 6) & 1;
        int ll = tid & 63;
        int n = ll & 15, kg = ll >> 4;
        int rl = nt * 16 + n;
        size_t grow = (size_t)t * 1024 + (size_t)b0 * S_DIM + rl;
        zfrag[kt][nt][ll] = *(const uint4*)&ztraj_u[grow * 64 + kt * 16 + kg * 4];
    }
    __syncthreads();

    f16* pwf = (f16*)pwfrag;
    #pragma unroll
    for (int nt = 0; nt < 2; ++nt) {
        #pragma unroll
        for (int mt = 0; mt < 4; ++mt) {
            f32x4 acc = (f32x4)0.f;
            #pragma unroll
            for (int kt = 0; kt < 4; ++kt) acc = mfma16(wc[mt][kt], zfrag[kt][nt][l], acc);
            int c0 = wv * 64 + mt * 16 + 4 * lg;
            int rl = nt * 16 + lr;
            int bb = b0 + (rl >> 3);
            size_t hbs = ((size_t)t * B_DIM + bb) * H_DIM;
            uint2 hpv = *(const uint2*)&HpF[hbs + c0];
            float p0 = fmaxf(acc[0] + upk_lo(hpv.x), 0.f);
            float p1 = fmaxf(acc[1] + upk_hi(hpv.x), 0.f);
            float p2 = fmaxf(acc[2] + upk_lo(hpv.y), 0.f);
            float p3 = fmaxf(acc[3] + upk_hi(hpv.y), 0.f);
            int ktp = c0 >> 5;
            int lp  = lr + 16 * ((c0 >> 3) & 3);
            int off = c0 & 7;
            uint2 wp; wp.x = pk2(p0, p1); wp.y = pk2(p2, p3);
            *(uint2*)&pwf[(size_t)((ktp * 2 + nt) * 64 + lp) * 8 + off] = wp;
        }
    }
    __syncthreads();

    #pragma unroll
    for (int nt = 0; nt < 2; ++nt) {
        f32x4 acc = (f32x4)0.f;
        #pragma unroll
        for (int kt = 0; kt < 16; ++kt) acc = mfma16(wd[kt], pwfrag[kt][nt][l], acc);
        int m0 = wv * 16 + 4 * lg;
        int row = nt * 16 + lr;
        #pragma unroll
        for (int i = 0; i < 4; ++i) obuf[m0 + i][row] = acc[i];
    }
    __syncthreads();

    float racc = 0.f;
    {
        int row = tid >> 4;
        int d4 = (tid & 15) * 4;
        int bb = b0 + (row >> 3);
        float mt = MtM[(size_t)t * B_DIM + bb];
        #pragma unroll
        for (int i = 0; i < 4; ++i) {
            int d = d4 + i;
            float mean = obuf[d][row] + bp2[d];
            float lv   = obuf[d + 64][row] + bp2[64 + d];
            float xv = X[((size_t)t * B_DIM + bb) * DIN + d];
            float dm = xv - mean;
            float nll = 0.5f * (LOG_2PI_F + lv + dm * dm * __expf(-lv));
            racc = fmaf(mt, nll, racc);
        }
    }
    red2[tid] = racc;
    __syncthreads();
    for (int st = 256; st > 0; st >>= 1) {
        if (tid < st) red2[tid] += red2[tid + st];
        __syncthreads();
    }
    if (tid == 0) atomicAdd(loss_acc + 1, red2[0]);
}

// ---------------------------------------------------------------------------
// K4: finalize
// ---------------------------------------------------------------------------
__global__ void k4_final(const float* __restrict__ loss_acc, float* __restrict__ out)
{
    if (threadIdx.x == 0 && blockIdx.x == 0) {
        float kld   = loss_acc[0] * (0.5f * DT_F / (float)(B_DIM * S_DIM));
        float recon = loss_acc[1] * (1.0f / (float)(B_DIM * S_DIM));
        out[131072] = recon + kld;
        out[131073] = recon;
        out[131074] = kld;
    }
}

// ---------------------------------------------------------------------------
extern "C" void kernel_launch(void* const* d_in, const int* in_sizes, int n_in,
                              void* d_out, int out_size, void* d_ws, size_t ws_size,
                              hipStream_t stream)
{
    const float* X        = (const float*)d_in[0];
    const float* M        = (const float*)d_in[1];
    const float* cov      = (const float*)d_in[2];
    const float* path_h   = (const float*)d_in[3];
    const float* path_hpos= (const float*)d_in[4];
    const float* noise    = (const float*)d_in[5];
    const float* Wc1 = (const float*)d_in[6];
    const float* bc1 = (const float*)d_in[7];
    const float* Wc2 = (const float*)d_in[8];
    const float* bc2 = (const float*)d_in[9];
    const float* Wd1 = (const float*)d_in[10];
    const float* bd1 = (const float*)d_in[11];
    const float* Wd2 = (const float*)d_in[12];
    const float* bd2 = (const float*)d_in[13];
    const float* Wf1 = (const float*)d_in[14];
    const float* bf1 = (const float*)d_in[15];
    const float* Wf2 = (const float*)d_in[16];
    const float* bf2 = (const float*)d_in[17];
    const float* Wp1 = (const float*)d_in[18];
    const float* bp1 = (const float*)d_in[19];
    const float* Wp2 = (const float*)d_in[20];
    const float* bp2 = (const float*)d_in[21];
    float* out = (float*)d_out;

    // workspace layout (bytes, 256-aligned)
    char* ws = (char*)d_ws;
    size_t o = 0;
    float* z_state = (float*)(ws + o); o += 524288;
    float* loss    = (float*)(ws + o); o += 256;
    f16* WA   = (f16*)(ws + o); o += 131072;
    f16* WB   = (f16*)(ws + o); o += 131072;
    f16* WC   = (f16*)(ws + o); o += 131072;
    f16* WD   = (f16*)(ws + o); o += 131072;
    f16* W1A  = (f16*)(ws + o); o += 262144;
    f16* WF1  = (f16*)(ws + o); o += 262144;
    f16* WP1A = (f16*)(ws + o); o += 262144;
    f16* WF2  = (f16*)(ws + o); o += 131072;
    f16* HprF = (f16*)(ws + o); o += 16777216;
    f16* HpoF = (f16*)(ws + o); o += 16777216;
    f16* HpF  = (f16*)(ws + o); o += 16777216;
    float* Diff = (float*)(ws + o); o += 8388608;
    float* MtM  = (float*)(ws + o); o += 65536;
    unsigned* ztraj = (unsigned*)(ws + o); o += 33554432;

    kw_frag<<<2816, 256, 0, stream>>>(Wd1, Wd2, Wp1, Wp2, Wf1, Wf2,
                                      WA, WB, WC, WD, W1A, WF1, WP1A, WF2);
    k0_init<<<B_DIM, 128, 0, stream>>>(cov, Wc1, bc1, Wc2, bc2, z_state, loss);
    k1_pre<<<256, 512, 0, stream>>>(path_h, path_hpos, M,
                                    W1A, WF1, WP1A, WF2,
                                    bd1, bf1, bf2, bp1,
                                    HprF, HpoF, HpF, Diff, MtM);
    k2_scan<<<256, 512, 0, stream>>>(WA, WB, HprF, HpoF, Diff, noise, bd2,
                                     z_state, ztraj, out, loss);
    k3_recon<<<4096, 512, 0, stream>>>(WC, WD, HpF, ztraj, X, MtM, bp2, loss);
    k4_final<<<1, 64, 0, stream>>>(loss, out);
}